// Round 1
// baseline (918.670 us; speedup 1.0000x reference)
//
#include <hip/hip_runtime.h>
#include <hip/hip_bf16.h>

// ---------------------------------------------------------------------------
// Treensformer block: x += MHSA(LN1(x)); x += BranchMLP(LN2(x))
// B=64, N_NODES=341, E=512, H=8, hd=64, 4*E=2048, N_LEVELS=4
// R1: MFMA flash attention. R5: branch-MLP ancestor dedup (Y_s by source
//     depth s; combine kernel). Old GEMM: 128x128xBK32, 2 syncthreads/step.
// R6: ALL GEMMs -> gemm256: 256x256xBK64 deep-pipelined MFMA kernel.
//     Rationale: w2 GEMM counters showed MfmaUtil 12.7 / VALUBusy 9.2 /
//     HBM 23% / Occ 26% -> latency-bound on the 2-barrier-per-32K
//     structure (318 TF). New structure (plain-HIP port of the 8-phase
//     template): 8 waves (2Mx4N), double-buffered 128KB LDS,
//     global_load_lds dwordx4 staging, XOR slot swizzle (linear LDS dest +
//     inverse-swizzled global source + swizzled ds_read), raw s_barrier
//     phases with counted s_waitcnt vmcnt(4) (never 0 in steady state:
//     prefetch runs 4-7 phases ahead of use), s_setprio(1) around MFMA
//     clusters, bijective XCD swizzle + A-major block order.
//     Schedule (per K-tile t, 4 phases):
//       ph1: ds_read A[0..3]+B[0..1] | issue A-half0(t+1) | bar;lgkm0;16 MFMA;bar
//       ph2: ds_read B[2..3]         | issue A-half1(t+1) | bar;lgkm0;16 MFMA;bar
//       ph3: ds_read A[4..7]         | issue B-half0(t+2) | bar;lgkm0;16 MFMA;bar
//       ph4:                           issue B-half1(t+2) | 16 MFMA; vmcnt(4); bar
//     Safety: a region is overwritten only >=1 barrier after its last
//     ds_read (A halves free after ph3, B halves after ph2); vmcnt(4) at
//     ph4 leaves exactly the 2 newest half-tiles (B of t+2) in flight and
//     guarantees tile t+1 fully landed; the ph4 barrier after each wave's
//     own vmcnt makes landing visible cross-wave.
// ---------------------------------------------------------------------------

typedef __attribute__((ext_vector_type(8))) __bf16 bf16x8;
typedef __attribute__((ext_vector_type(4))) float f32x4;
typedef __attribute__((ext_vector_type(4))) unsigned int u32x4;

#define GF_RELU    1
#define GF_OUTBF16 2

static __device__ __forceinline__ bf16x8 bzero8() {
    u32x4 z = {0u, 0u, 0u, 0u};
    return __builtin_bit_cast(bf16x8, z);
}

// ---------------------------------------------------------------------------
// Weight transpose+convert: out[n*K + k] = bf16(in[k*N + n]); K is pow2.
// ---------------------------------------------------------------------------
__global__ void transpose_bf16_kernel(const float* __restrict__ in,
                                      __hip_bfloat16* __restrict__ out,
                                      int K, int N, int log2K) {
    int idx = blockIdx.x * 256 + threadIdx.x;
    if (idx >= K * N) return;
    int n = idx >> log2K;
    int k = idx & (K - 1);
    out[idx] = __float2bfloat16(in[(size_t)k * N + n]);
}

// ---------------------------------------------------------------------------
// Pack mlp_M (5,5,2048,512) fp32 -> Wcat bf16 grouped by source depth s.
// ---------------------------------------------------------------------------
__global__ void pack_wcat_kernel(const float* __restrict__ M,
                                 __hip_bfloat16* __restrict__ out) {
    int p = blockIdx.y;
    int s, d;
    if (p < 5)       { s = 0; d = p; }
    else if (p < 9)  { s = 1; d = p - 4; }
    else if (p < 12) { s = 2; d = p - 7; }
    else if (p < 14) { s = 3; d = p - 9; }
    else             { s = 4; d = 4; }
    const int base_lut[5] = {0, 5, 9, 12, 14};
    size_t idx = (size_t)blockIdx.x * 256 + threadIdx.x;  // 0 .. 2048*512-1
    const size_t MB = 2048ull * 512;
    out[(size_t)base_lut[s] * MB + (size_t)(d - s) * MB + idx] =
        __float2bfloat16(M[((size_t)d * 5 + s) * MB + idx]);
}

// ---------------------------------------------------------------------------
// LayerNorm over E=512, one block (256 threads) per token; writes bf16.
// ---------------------------------------------------------------------------
__global__ __launch_bounds__(256) void ln_kernel(const float* __restrict__ x,
                                                 const float* __restrict__ g,
                                                 const float* __restrict__ b,
                                                 __hip_bfloat16* __restrict__ out) {
    int tok = blockIdx.x;
    const float* xr = x + (size_t)tok * 512;
    int t = threadIdx.x;
    float v0 = xr[t], v1 = xr[t + 256];
    float s = v0 + v1;
    float s2 = v0 * v0 + v1 * v1;
    #pragma unroll
    for (int o = 32; o > 0; o >>= 1) {
        s  += __shfl_down(s, o);
        s2 += __shfl_down(s2, o);
    }
    __shared__ float ps[4], ps2[4];
    int w = t >> 6, lane = t & 63;
    if (lane == 0) { ps[w] = s; ps2[w] = s2; }
    __syncthreads();
    if (t == 0) {
        float ts = 0.f, ts2 = 0.f;
        #pragma unroll
        for (int i = 0; i < 4; i++) { ts += ps[i]; ts2 += ps2[i]; }
        ps[0] = ts * (1.f / 512.f);
        ps2[0] = ts2 * (1.f / 512.f);
    }
    __syncthreads();
    float m = ps[0];
    float var = ps2[0] - m * m;
    float r = rsqrtf(var + 1e-5f);
    out[(size_t)tok * 512 + t]       = __float2bfloat16((v0 - m) * r * g[t] + b[t]);
    out[(size_t)tok * 512 + t + 256] = __float2bfloat16((v1 - m) * r * g[t + 256] + b[t + 256]);
}

// ---------------------------------------------------------------------------
// MFMA flash attention (unchanged from R2).
// ---------------------------------------------------------------------------
#define ATT_STR 72
__global__ __launch_bounds__(256) void attn_mfma_kernel(const __hip_bfloat16* __restrict__ qkv,
                                                        __hip_bfloat16* __restrict__ ctx) {
    __shared__ __bf16 kt_lds[64 * ATT_STR];
    __shared__ __bf16 vt_lds[64 * ATT_STR];
    __shared__ __bf16 pbuf[4 * 48 * ATT_STR];

    const int bh = blockIdx.x;
    const int half = blockIdx.y;
    const int b = bh >> 3, h = bh & 7;
    const int tid = threadIdx.x;
    const int w = tid >> 6, lane = tid & 63;
    const int q = lane >> 4, l16 = lane & 15;
    const int rowbase = half * 192 + w * 48;
    __bf16* pw = pbuf + w * 48 * ATT_STR;

    bf16x8 qf[3][2];
    #pragma unroll
    for (int mi = 0; mi < 3; mi++) {
        int row = rowbase + mi * 16 + l16;
        #pragma unroll
        for (int ks = 0; ks < 2; ks++) {
            if (row < 341)
                qf[mi][ks] = *(const bf16x8*)(qkv + (size_t)(b * 341 + row) * 1536 +
                                              h * 64 + ks * 32 + q * 8);
            else
                qf[mi][ks] = bzero8();
        }
    }

    f32x4 O[3][4];
    float mrun[3][4], lrun[3][4];
    #pragma unroll
    for (int mi = 0; mi < 3; mi++) {
        #pragma unroll
        for (int ni = 0; ni < 4; ni++) { f32x4 z = {0.f,0.f,0.f,0.f}; O[mi][ni] = z; }
        #pragma unroll
        for (int rr = 0; rr < 4; rr++) { mrun[mi][rr] = -1e30f; lrun[mi][rr] = 0.f; }
    }

    for (int kt6 = 0; kt6 < 6; kt6++) {
        const int kbase = kt6 * 64;
        __syncthreads();
        {
            int key = tid >> 2, kg = tid & 3;
            int gk = kbase + key;
            bf16x8 a0 = bzero8(), a1 = bzero8();
            if (gk < 341) {
                const __hip_bfloat16* src =
                    qkv + (size_t)(b * 341 + gk) * 1536 + 512 + h * 64 + kg * 16;
                a0 = *(const bf16x8*)src;
                a1 = *(const bf16x8*)(src + 8);
            }
            *(bf16x8*)(kt_lds + key * ATT_STR + kg * 16)     = a0;
            *(bf16x8*)(kt_lds + key * ATT_STR + kg * 16 + 8) = a1;
        }
        {
            int key = tid & 63, dg = tid >> 6;
            int gk = kbase + key;
            bf16x8 a0 = bzero8(), a1 = bzero8();
            if (gk < 341) {
                const __hip_bfloat16* src =
                    qkv + (size_t)(b * 341 + gk) * 1536 + 1024 + h * 64 + dg * 16;
                a0 = *(const bf16x8*)src;
                a1 = *(const bf16x8*)(src + 8);
            }
            #pragma unroll
            for (int j = 0; j < 8; j++) {
                vt_lds[(dg * 16 + j) * ATT_STR + key]     = a0[j];
                vt_lds[(dg * 16 + 8 + j) * ATT_STR + key] = a1[j];
            }
        }
        __syncthreads();

        f32x4 S[3][4];
        #pragma unroll
        for (int mi = 0; mi < 3; mi++)
            #pragma unroll
            for (int ni = 0; ni < 4; ni++) { f32x4 z = {0.f,0.f,0.f,0.f}; S[mi][ni] = z; }
        #pragma unroll
        for (int ks = 0; ks < 2; ks++) {
            bf16x8 bf_[4];
            #pragma unroll
            for (int ni = 0; ni < 4; ni++)
                bf_[ni] = *(const bf16x8*)(kt_lds + (ni * 16 + l16) * ATT_STR + ks * 32 + q * 8);
            #pragma unroll
            for (int mi = 0; mi < 3; mi++)
                #pragma unroll
                for (int ni = 0; ni < 4; ni++)
                    S[mi][ni] = __builtin_amdgcn_mfma_f32_16x16x32_bf16(qf[mi][ks], bf_[ni],
                                                                        S[mi][ni], 0, 0, 0);
        }

        float cmask[4];
        #pragma unroll
        for (int ni = 0; ni < 4; ni++)
            cmask[ni] = (kbase + ni * 16 + l16 < 341) ? 0.f : -1e30f;

        #pragma unroll
        for (int mi = 0; mi < 3; mi++) {
            #pragma unroll
            for (int rr = 0; rr < 4; rr++) {
                float rmax = -1e30f;
                #pragma unroll
                for (int ni = 0; ni < 4; ni++)
                    rmax = fmaxf(rmax, fmaf(S[mi][ni][rr], 0.125f, cmask[ni]));
                rmax = fmaxf(rmax, __shfl_xor(rmax, 1));
                rmax = fmaxf(rmax, __shfl_xor(rmax, 2));
                rmax = fmaxf(rmax, __shfl_xor(rmax, 4));
                rmax = fmaxf(rmax, __shfl_xor(rmax, 8));
                float mnew = fmaxf(mrun[mi][rr], rmax);
                float alpha = __expf(mrun[mi][rr] - mnew);
                mrun[mi][rr] = mnew;
                float psum = 0.f;
                #pragma unroll
                for (int ni = 0; ni < 4; ni++) {
                    float p = __expf(fmaf(S[mi][ni][rr], 0.125f, cmask[ni]) - mnew);
                    S[mi][ni][rr] = p;
                    psum += p;
                    O[mi][ni][rr] *= alpha;
                }
                psum += __shfl_xor(psum, 1);
                psum += __shfl_xor(psum, 2);
                psum += __shfl_xor(psum, 4);
                psum += __shfl_xor(psum, 8);
                lrun[mi][rr] = lrun[mi][rr] * alpha + psum;
            }
            #pragma unroll
            for (int ni = 0; ni < 4; ni++)
                #pragma unroll
                for (int rr = 0; rr < 4; rr++)
                    pw[(mi * 16 + q * 4 + rr) * ATT_STR + ni * 16 + l16] =
                        (__bf16)S[mi][ni][rr];
        }
        __syncthreads();

        #pragma unroll
        for (int ks = 0; ks < 2; ks++) {
            bf16x8 pf[3], vf[4];
            #pragma unroll
            for (int mi = 0; mi < 3; mi++)
                pf[mi] = *(const bf16x8*)(pw + (mi * 16 + l16) * ATT_STR + ks * 32 + q * 8);
            #pragma unroll
            for (int ni = 0; ni < 4; ni++)
                vf[ni] = *(const bf16x8*)(vt_lds + (ni * 16 + l16) * ATT_STR + ks * 32 + q * 8);
            #pragma unroll
            for (int mi = 0; mi < 3; mi++)
                #pragma unroll
                for (int ni = 0; ni < 4; ni++)
                    O[mi][ni] = __builtin_amdgcn_mfma_f32_16x16x32_bf16(pf[mi], vf[ni],
                                                                        O[mi][ni], 0, 0, 0);
        }
    }

    #pragma unroll
    for (int mi = 0; mi < 3; mi++) {
        #pragma unroll
        for (int rr = 0; rr < 4; rr++) {
            int row = rowbase + mi * 16 + q * 4 + rr;
            if (row >= 341) continue;
            float inv = 1.f / lrun[mi][rr];
            __hip_bfloat16* op = ctx + (size_t)(b * 341 + row) * 512 + h * 64;
            #pragma unroll
            for (int ni = 0; ni < 4; ni++)
                op[ni * 16 + l16] = __float2bfloat16(O[mi][ni][rr] * inv);
        }
    }
}

// ---------------------------------------------------------------------------
// gemm256: C(Mrows,N) = A(Mrows,K) @ Bt(N,K)^T [+bias][+resid][relu]
// 256x256 tile, BK=64, 512 threads = 8 waves (2M x 4N), per-wave C 128x64.
// Deep pipeline per header comment. Requires K % 64 == 0, K >= 128,
// N % 256 == 0. GATHER: A row gr -> b = gr>>2s, node = offs[s] + (gr&mask).
// ---------------------------------------------------------------------------
__device__ __forceinline__ void gload16(const __hip_bfloat16* g, __bf16* l) {
    __builtin_amdgcn_global_load_lds(
        (const __attribute__((address_space(1))) void*)g,
        (__attribute__((address_space(3))) void*)l, 16, 0, 0);
}

#define FULL_BAR() do { asm volatile("" ::: "memory");                        \
    __builtin_amdgcn_sched_barrier(0);                                        \
    __builtin_amdgcn_s_barrier();                                             \
    __builtin_amdgcn_sched_barrier(0); } while (0)

#define LGKM0() do {                                                          \
    asm volatile("s_waitcnt lgkmcnt(0)" ::: "memory");                        \
    __builtin_amdgcn_sched_barrier(0); } while (0)

// stage one half-tile (128 rows x 64 cols bf16): 2 global_load_lds dwordx4
// per wave; LDS dest linear, global source pre-swizzled (slot ^ row&7).
#define STAGE(arr, pr, isB, h, koff) do {                                     \
    __bf16* _d = &smem[((((((pr) << 1) + (isB)) << 1) + (h)) << 13) + w * 1024]; \
    gload16(arr[h][0] + (koff), _d);                                          \
    gload16(arr[h][1] + (koff), _d + 512);                                    \
} while (0)

template <bool GATHER>
__global__ __launch_bounds__(512, 2) void gemm256(
    const __hip_bfloat16* __restrict__ A, const __hip_bfloat16* __restrict__ Bt,
    const float* __restrict__ bias, const float* __restrict__ resid,
    float* __restrict__ Cf, __hip_bfloat16* __restrict__ Cb,
    int Mrows, int N, int K, int flags, int depth, int gridN) {
    __shared__ __align__(128) __bf16 smem[65536];  // 128 KiB: 2buf x {A,B} x 2half x 8192

    // bijective XCD-aware remap (m204), then A-major decode: consecutive
    // logical blocks share the A row-panel -> per-XCD L2 A reuse.
    const int nwg = gridDim.x;
    const int bid = blockIdx.x;
    const int xcd = bid & 7, o = bid >> 3;
    const int qq = nwg >> 3, rr = nwg & 7;
    const int lin = (xcd < rr ? xcd * (qq + 1) : rr * (qq + 1) + (xcd - rr) * qq) + o;
    const int bx = lin / gridN;
    const int by = lin - bx * gridN;
    const int bm0 = bx << 8, bn0 = by << 8;

    const int tid = threadIdx.x;
    const int w = tid >> 6, l = tid & 63;
    const int l16 = l & 15, q = l >> 4;
    const int wm = w >> 2, wn = w & 3;
    const int lr8 = l >> 3;               // row within 8-row staging chunk
    const int slog = (l & 7) ^ lr8;       // inverse-swizzled logical 16B slot

    // staging source pointers: [half][j], j = chunk parity within wave
    const __hip_bfloat16* aptr[2][2];
    const __hip_bfloat16* bptr[2][2];
    #pragma unroll
    for (int h = 0; h < 2; h++)
        #pragma unroll
        for (int j = 0; j < 2; j++) {
            int lr = (w * 2 + j) * 8 + lr8;        // local row in half (0..127)
            int grow = bm0 + h * 128 + lr;
            if (grow > Mrows - 1) grow = Mrows - 1;   // clamp; masked at store
            size_t abase;
            if (GATHER) {
                const int dsh = depth << 1;
                const int bmask = (1 << dsh) - 1;
                int bb = grow >> dsh;
                int ii = grow & bmask;
                int node = (0x55555555 & bmask) + ii;
                abase = ((size_t)(bb * 341 + node)) << 9;
            } else {
                abase = (size_t)grow * K;
            }
            aptr[h][j] = A + abase + slog * 8;
            bptr[h][j] = Bt + (size_t)(bn0 + h * 128 + lr) * K + slog * 8;
        }

    // swizzled ds_read slot offsets (elements) for k-slice 0 / 1
    const int sl0 = ((q ^ (l16 & 7)) << 3);
    const int sl1 = (((4 + q) ^ (l16 & 7)) << 3);

    f32x4 acc[8][4];
    #pragma unroll
    for (int i = 0; i < 8; i++)
        #pragma unroll
        for (int j = 0; j < 4; j++) {
            f32x4 z = {0.f, 0.f, 0.f, 0.f};
            acc[i][j] = z;
        }

    // prologue: A(0), B(0), B(1), A(1)  (order matters for vmcnt counting)
    STAGE(aptr, 0, 0, 0, 0);  STAGE(aptr, 0, 0, 1, 0);
    STAGE(bptr, 0, 1, 0, 0);  STAGE(bptr, 0, 1, 1, 0);
    STAGE(bptr, 1, 1, 0, 64); STAGE(bptr, 1, 1, 1, 64);
    STAGE(aptr, 1, 0, 0, 64); STAGE(aptr, 1, 0, 1, 64);
    asm volatile("s_waitcnt vmcnt(8)" ::: "memory");  // tile0 landed; tile1 in flight
    __builtin_amdgcn_sched_barrier(0);
    FULL_BAR();

    const int NT = K >> 6;
    bf16x8 af[4][2], b0[2][2], b1[2][2];

    for (int t = 0; t < NT; ++t) {
        const int p = t & 1;
        const int aro = ((p << 2) + wm) << 13;                         // A half wm
        const int bro = ((((p << 1) + 1) << 1) + (wn >> 1)) * 8192 + ((wn & 1) << 12);

        // ---- phase 1: ds_read A[0..3]x2 + B[0..1]x2 (12); issue A-half0(t+1)
        #pragma unroll
        for (int mi = 0; mi < 4; mi++) {
            af[mi][0] = *(const bf16x8*)&smem[aro + (mi * 16 + l16) * 64 + sl0];
            af[mi][1] = *(const bf16x8*)&smem[aro + (mi * 16 + l16) * 64 + sl1];
        }
        #pragma unroll
        for (int ni = 0; ni < 2; ni++) {
            b0[ni][0] = *(const bf16x8*)&smem[bro + (ni * 16 + l16) * 64 + sl0];
            b0[ni][1] = *(const bf16x8*)&smem[bro + (ni * 16 + l16) * 64 + sl1];
        }
        if (t >= 1 && t + 1 < NT) STAGE(aptr, (t + 1) & 1, 0, 0, (t + 1) << 6);
        FULL_BAR();
        LGKM0();
        __builtin_amdgcn_s_setprio(1);
        #pragma unroll
        for (int ks = 0; ks < 2; ks++)
            #pragma unroll
            for (int mi = 0; mi < 4; mi++)
                #pragma unroll
                for (int ni = 0; ni < 2; ni++)
                    acc[mi][ni] = __builtin_amdgcn_mfma_f32_16x16x32_bf16(
                        af[mi][ks], b0[ni][ks], acc[mi][ni], 0, 0, 0);
        __builtin_amdgcn_s_setprio(0);
        FULL_BAR();

        // ---- phase 2: ds_read B[2..3]x2 (4); issue A-half1(t+1)
        #pragma unroll
        for (int ni = 0; ni < 2; ni++) {
            b1[ni][0] = *(const bf16x8*)&smem[bro + ((ni + 2) * 16 + l16) * 64 + sl0];
            b1[ni][1] = *(const bf16x8*)&smem[bro + ((ni + 2) * 16 + l16) * 64 + sl1];
        }
        if (t >= 1 && t + 1 < NT) STAGE(aptr, (t + 1) & 1, 0, 1, (t + 1) << 6);
        FULL_BAR();
        LGKM0();
        __builtin_amdgcn_s_setprio(1);
        #pragma unroll
        for (int ks = 0; ks < 2; ks++)
            #pragma unroll
            for (int mi = 0; mi < 4; mi++)
                #pragma unroll
                for (int ni = 0; ni < 2; ni++)
                    acc[mi][ni + 2] = __builtin_amdgcn_mfma_f32_16x16x32_bf16(
                        af[mi][ks], b1[ni][ks], acc[mi][ni + 2], 0, 0, 0);
        __builtin_amdgcn_s_setprio(0);
        FULL_BAR();

        // ---- phase 3: ds_read A[4..7]x2 (8); issue B-half0(t+2)
        #pragma unroll
        for (int mi = 0; mi < 4; mi++) {
            af[mi][0] = *(const bf16x8*)&smem[aro + ((mi + 4) * 16 + l16) * 64 + sl0];
            af[mi][1] = *(const bf16x8*)&smem[aro + ((mi + 4) * 16 + l16) * 64 + sl1];
        }
        if (t + 2 < NT) STAGE(bptr, p, 1, 0, (t + 2) << 6);
        FULL_BAR();
        LGKM0();
        __builtin_amdgcn_s_setprio(1);
        #pragma unroll
        for (int ks = 0; ks < 2; ks++)
            #pragma unroll
            for (int mi = 0; mi < 4; mi++)
                #pragma unroll
                for (int ni = 0; ni < 2; ni++)
                    acc[mi + 4][ni + 2] = __builtin_amdgcn_mfma_f32_16x16x32_bf16(
                        af[mi][ks], b1[ni][ks], acc[mi + 4][ni + 2], 0, 0, 0);
        __builtin_amdgcn_s_setprio(0);
        FULL_BAR();

        // ---- phase 4: issue B-half1(t+2); MFMA (regs only); counted vmcnt
        if (t + 2 < NT) STAGE(bptr, p, 1, 1, (t + 2) << 6);
        __builtin_amdgcn_s_setprio(1);
        #pragma unroll
        for (int ks = 0; ks < 2; ks++)
            #pragma unroll
            for (int mi = 0; mi < 4; mi++)
                #pragma unroll
                for (int ni = 0; ni < 2; ni++)
                    acc[mi + 4][ni] = __builtin_amdgcn_mfma_f32_16x16x32_bf16(
                        af[mi][ks], b0[ni][ks], acc[mi + 4][ni], 0, 0, 0);
        __builtin_amdgcn_s_setprio(0);
        if (t + 1 < NT) {
            if (t + 2 < NT) { asm volatile("s_waitcnt vmcnt(4)" ::: "memory"); }
            else            { asm volatile("s_waitcnt vmcnt(0)" ::: "memory"); }
            __builtin_amdgcn_sched_barrier(0);
        }
        FULL_BAR();
    }

    // epilogue
    #pragma unroll
    for (int mi = 0; mi < 8; mi++) {
        #pragma unroll
        for (int rr2 = 0; rr2 < 4; rr2++) {
            int grow = bm0 + wm * 128 + mi * 16 + q * 4 + rr2;
            if (grow >= Mrows) continue;
            size_t obase = (size_t)grow * N;
            #pragma unroll
            for (int ni = 0; ni < 4; ni++) {
                int col = bn0 + wn * 64 + ni * 16 + l16;
                float v = acc[mi][ni][rr2];
                if (bias) v += bias[col];
                if (resid) v += resid[obase + col];
                if (flags & GF_RELU) v = fmaxf(v, 0.f);
                if (flags & GF_OUTBF16)
                    Cb[obase + col] = __float2bfloat16(v);
                else
                    Cf[obase + col] = v;
            }
        }
    }
}

// ---------------------------------------------------------------------------
// Combine: h[b,node@d,:] = ReLU( sum_{s<=d} Y_s[...] + b1[node] )  (unchanged)
// ---------------------------------------------------------------------------
__global__ __launch_bounds__(256) void combine_kernel(const __hip_bfloat16* __restrict__ Y,
                                                      const float* __restrict__ b1,
                                                      __hip_bfloat16* __restrict__ h) {
    const size_t yoff[5] = {0, 655360, 2752512, 9043968, 25821184};
    int row = blockIdx.x;
    int b = row / 341;
    int node = row - b * 341;
    int d = (node >= 85) ? 4 : (node >= 21) ? 3 : (node >= 5) ? 2 : (node >= 1) ? 1 : 0;
    int i = node - (0x55555555 & ((1 << (d << 1)) - 1));
    int j = threadIdx.x << 3;

    float acc[8];
    const float* bp = b1 + (size_t)node * 2048 + j;
    f32x4 b0 = *(const f32x4*)bp;
    f32x4 b4 = *(const f32x4*)(bp + 4);
    #pragma unroll
    for (int u = 0; u < 4; u++) { acc[u] = b0[u]; acc[u + 4] = b4[u]; }

    #pragma unroll
    for (int s = 0; s < 5; s++) {
        if (s <= d) {
            int a = i >> ((d - s) << 1);
            int width = (5 - s) << 11;
            const bf16x8 v = *(const bf16x8*)(Y + yoff[s] +
                (size_t)((b << (s << 1)) + a) * width + ((d - s) << 11) + j);
            #pragma unroll
            for (int u = 0; u < 8; u++) acc[u] += (float)v[u];
        }
    }
    bf16x8 o;
    #pragma unroll
    for (int u = 0; u < 8; u++) o[u] = (__bf16)fmaxf(acc[u], 0.f);
    *(bf16x8*)(h + (size_t)row * 2048 + j) = o;
}

// ---------------------------------------------------------------------------
extern "C" void kernel_launch(void* const* d_in, const int* in_sizes, int n_in,
                              void* d_out, int out_size, void* d_ws, size_t ws_size,
                              hipStream_t stream) {
    const float* x      = (const float*)d_in[0];
    const float* ln1_g  = (const float*)d_in[1];
    const float* ln1_b  = (const float*)d_in[2];
    const float* w_qkv  = (const float*)d_in[3];
    const float* b_qkv  = (const float*)d_in[4];
    const float* w_proj = (const float*)d_in[5];
    const float* b_proj = (const float*)d_in[6];
    const float* ln2_g  = (const float*)d_in[7];
    const float* ln2_b  = (const float*)d_in[8];
    const float* mlp_M  = (const float*)d_in[9];
    const float* mlp_b1 = (const float*)d_in[10];
    const float* w2     = (const float*)d_in[11];
    const float* b2     = (const float*)d_in[12];
    float* out = (float*)d_out;

    const int M = 64 * 341;  // 21824 rows

    char* ws = (char*)d_ws;
    size_t off = 0;
    auto alloc = [&](size_t bytes) -> char* {
        char* p = ws + off;
        off += (bytes + 255) & ~(size_t)255;
        return p;
    };
    __hip_bfloat16* xn     = (__hip_bfloat16*)alloc((size_t)M * 512 * 2);
    __hip_bfloat16* wqkvT  = (__hip_bfloat16*)alloc(1536ull * 512 * 2);
    __hip_bfloat16* wprojT = (__hip_bfloat16*)alloc(512ull * 512 * 2);
    __hip_bfloat16* w2T    = (__hip_bfloat16*)alloc(512ull * 2048 * 2);
    __hip_bfloat16* wcat   = (__hip_bfloat16*)alloc(15ull * 2048 * 512 * 2);
    __hip_bfloat16* hbuf   = (__hip_bfloat16*)alloc((size_t)M * 2048 * 2);
    // shared region: qkv+ctx (attention phase) overlaid by Y (branch phase)
    const size_t qkv_bytes = (size_t)M * 1536 * 2;            // 67,043,328
    const size_t y_bytes   = 59375616ull * 2;                 // 118,751,232
    char* shared = alloc(y_bytes);                            // >= qkv+ctx
    __hip_bfloat16* qkv = (__hip_bfloat16*)shared;
    __hip_bfloat16* ctx = (__hip_bfloat16*)(shared + qkv_bytes);
    __hip_bfloat16* Y   = (__hip_bfloat16*)shared;
    if (off > ws_size) return;  // workspace too small -> clean validation failure

    auto g256 = [&](bool gather, const __hip_bfloat16* A, const __hip_bfloat16* Bt,
                    const float* bias, const float* resid, float* Cf,
                    __hip_bfloat16* Cb, int Mr, int N, int K, int flags, int depth) {
        int gm = (Mr + 255) >> 8, gn = N >> 8;
        if (gather)
            gemm256<true><<<dim3(gm * gn), 512, 0, stream>>>(
                A, Bt, bias, resid, Cf, Cb, Mr, N, K, flags, depth, gn);
        else
            gemm256<false><<<dim3(gm * gn), 512, 0, stream>>>(
                A, Bt, bias, resid, Cf, Cb, Mr, N, K, flags, depth, gn);
    };

    // weight prep
    transpose_bf16_kernel<<<(512 * 1536 + 255) / 256, 256, 0, stream>>>(w_qkv, wqkvT, 512, 1536, 9);
    transpose_bf16_kernel<<<(512 * 512 + 255) / 256, 256, 0, stream>>>(w_proj, wprojT, 512, 512, 9);
    transpose_bf16_kernel<<<(2048 * 512 + 255) / 256, 256, 0, stream>>>(w2, w2T, 2048, 512, 11);
    pack_wcat_kernel<<<dim3(4096, 15), 256, 0, stream>>>(mlp_M, wcat);

    // attention path
    ln_kernel<<<M, 256, 0, stream>>>(x, ln1_g, ln1_b, xn);
    g256(false, xn, wqkvT, b_qkv, nullptr, nullptr, qkv, M, 1536, 512, GF_OUTBF16, 0);
    attn_mfma_kernel<<<dim3(512, 2), 256, 0, stream>>>(qkv, ctx);
    g256(false, ctx, wprojT, b_proj, x, out, nullptr, M, 512, 512, 0, 0);

    // branch MLP path (dedup by source depth s)
    ln_kernel<<<M, 256, 0, stream>>>(out, ln2_g, ln2_b, xn);
    const size_t yoff[5]     = {0, 655360, 2752512, 9043968, 25821184};
    const size_t wcat_off[5] = {0, 5, 9, 12, 14};  // in 2048*512 units
    for (int s = 0; s <= 4; s++) {
        int rows = 64 << (2 * s);
        int Ns = (5 - s) * 2048;
        g256(true, xn, wcat + wcat_off[s] * (2048ull * 512), nullptr, nullptr, nullptr,
             Y + yoff[s], rows, Ns, 512, GF_OUTBF16, s);
    }
    combine_kernel<<<M, 256, 0, stream>>>(Y, mlp_b1, hbuf);
    g256(false, hbuf, w2T, b2, out, out, nullptr, M, 512, 2048, 0, 0);
}

// Round 2
// 844.428 us; speedup vs baseline: 1.0879x; 1.0879x over previous
//
#include <hip/hip_runtime.h>
#include <hip/hip_bf16.h>

// ---------------------------------------------------------------------------
// Treensformer block: x += MHSA(LN1(x)); x += BranchMLP(LN2(x))
// B=64, N_NODES=341, E=512, H=8, hd=64, 4*E=2048, N_LEVELS=4
// R1: MFMA flash attention. R5: branch-MLP ancestor dedup (Y_s by source
//     depth s; combine kernel).
// R6: gemm256 256x256xBK64, 8 waves, dbuf LDS, glds staging, XOR swizzle,
//     XCD remap. RESULT: regressed (164us w2, MfmaUtil 10.8, conflicts 0,
//     FETCH 75MB). Diagnosis: 1 block/CU + A(t+1) staged only ~2.5 phases
//     before its vmcnt drain -> ~600cy exposed HBM latency per K-tile,
//     all 8 waves in lockstep; plus branch phase = 5 undersubscribed
//     dispatches (40..512 blocks).
// R7: (a) full-iteration prefetch distance: B(t+2) at ph3/ph4, A(t+2) at
//     ph4 (earliest legal points with 2 buffers: a region is staged only
//     after its last read of iter t has DRAINED + barrier). One counted
//     s_waitcnt vmcnt(8) per iteration keeps tile t+2's 8 loads in
//     flight, drains tile t+1 -> issue-to-wait 4-5 phases (~700-900cy).
//     (b) branch MLP: one fused 936-block dispatch (per-block s decode),
//     replacing 5 sequential small dispatches.
//     Schedule (per K-tile t, buffer p = t&1; t+2 lands in p):
//       ph1: ds_read A[0..3]+B[0..1]              | bar;lgkm0;16 MFMA;bar
//       ph2: ds_read B[2..3]                      | bar;lgkm0;16 MFMA;bar
//       ph3: ds_read A[4..7] | STAGE B-h0(t+2)    | bar;lgkm0;16 MFMA;bar
//       ph4: STAGE B-h1,A-h0,A-h1(t+2) | 16 MFMA | vmcnt(8); bar
// ---------------------------------------------------------------------------

typedef __attribute__((ext_vector_type(8))) __bf16 bf16x8;
typedef __attribute__((ext_vector_type(4))) float f32x4;
typedef __attribute__((ext_vector_type(4))) unsigned int u32x4;

#define GF_RELU    1
#define GF_OUTBF16 2

static __device__ __forceinline__ bf16x8 bzero8() {
    u32x4 z = {0u, 0u, 0u, 0u};
    return __builtin_bit_cast(bf16x8, z);
}

// ---------------------------------------------------------------------------
// Weight transpose+convert: out[n*K + k] = bf16(in[k*N + n]); K is pow2.
// ---------------------------------------------------------------------------
__global__ void transpose_bf16_kernel(const float* __restrict__ in,
                                      __hip_bfloat16* __restrict__ out,
                                      int K, int N, int log2K) {
    int idx = blockIdx.x * 256 + threadIdx.x;
    if (idx >= K * N) return;
    int n = idx >> log2K;
    int k = idx & (K - 1);
    out[idx] = __float2bfloat16(in[(size_t)k * N + n]);
}

// ---------------------------------------------------------------------------
// Pack mlp_M (5,5,2048,512) fp32 -> Wcat bf16 grouped by source depth s.
// ---------------------------------------------------------------------------
__global__ void pack_wcat_kernel(const float* __restrict__ M,
                                 __hip_bfloat16* __restrict__ out) {
    int p = blockIdx.y;
    int s, d;
    if (p < 5)       { s = 0; d = p; }
    else if (p < 9)  { s = 1; d = p - 4; }
    else if (p < 12) { s = 2; d = p - 7; }
    else if (p < 14) { s = 3; d = p - 9; }
    else             { s = 4; d = 4; }
    const int base_lut[5] = {0, 5, 9, 12, 14};
    size_t idx = (size_t)blockIdx.x * 256 + threadIdx.x;  // 0 .. 2048*512-1
    const size_t MB = 2048ull * 512;
    out[(size_t)base_lut[s] * MB + (size_t)(d - s) * MB + idx] =
        __float2bfloat16(M[((size_t)d * 5 + s) * MB + idx]);
}

// ---------------------------------------------------------------------------
// LayerNorm over E=512, one block (256 threads) per token; writes bf16.
// ---------------------------------------------------------------------------
__global__ __launch_bounds__(256) void ln_kernel(const float* __restrict__ x,
                                                 const float* __restrict__ g,
                                                 const float* __restrict__ b,
                                                 __hip_bfloat16* __restrict__ out) {
    int tok = blockIdx.x;
    const float* xr = x + (size_t)tok * 512;
    int t = threadIdx.x;
    float v0 = xr[t], v1 = xr[t + 256];
    float s = v0 + v1;
    float s2 = v0 * v0 + v1 * v1;
    #pragma unroll
    for (int o = 32; o > 0; o >>= 1) {
        s  += __shfl_down(s, o);
        s2 += __shfl_down(s2, o);
    }
    __shared__ float ps[4], ps2[4];
    int w = t >> 6, lane = t & 63;
    if (lane == 0) { ps[w] = s; ps2[w] = s2; }
    __syncthreads();
    if (t == 0) {
        float ts = 0.f, ts2 = 0.f;
        #pragma unroll
        for (int i = 0; i < 4; i++) { ts += ps[i]; ts2 += ps2[i]; }
        ps[0] = ts * (1.f / 512.f);
        ps2[0] = ts2 * (1.f / 512.f);
    }
    __syncthreads();
    float m = ps[0];
    float var = ps2[0] - m * m;
    float r = rsqrtf(var + 1e-5f);
    out[(size_t)tok * 512 + t]       = __float2bfloat16((v0 - m) * r * g[t] + b[t]);
    out[(size_t)tok * 512 + t + 256] = __float2bfloat16((v1 - m) * r * g[t + 256] + b[t + 256]);
}

// ---------------------------------------------------------------------------
// MFMA flash attention (unchanged from R2).
// ---------------------------------------------------------------------------
#define ATT_STR 72
__global__ __launch_bounds__(256) void attn_mfma_kernel(const __hip_bfloat16* __restrict__ qkv,
                                                        __hip_bfloat16* __restrict__ ctx) {
    __shared__ __bf16 kt_lds[64 * ATT_STR];
    __shared__ __bf16 vt_lds[64 * ATT_STR];
    __shared__ __bf16 pbuf[4 * 48 * ATT_STR];

    const int bh = blockIdx.x;
    const int half = blockIdx.y;
    const int b = bh >> 3, h = bh & 7;
    const int tid = threadIdx.x;
    const int w = tid >> 6, lane = tid & 63;
    const int q = lane >> 4, l16 = lane & 15;
    const int rowbase = half * 192 + w * 48;
    __bf16* pw = pbuf + w * 48 * ATT_STR;

    bf16x8 qf[3][2];
    #pragma unroll
    for (int mi = 0; mi < 3; mi++) {
        int row = rowbase + mi * 16 + l16;
        #pragma unroll
        for (int ks = 0; ks < 2; ks++) {
            if (row < 341)
                qf[mi][ks] = *(const bf16x8*)(qkv + (size_t)(b * 341 + row) * 1536 +
                                              h * 64 + ks * 32 + q * 8);
            else
                qf[mi][ks] = bzero8();
        }
    }

    f32x4 O[3][4];
    float mrun[3][4], lrun[3][4];
    #pragma unroll
    for (int mi = 0; mi < 3; mi++) {
        #pragma unroll
        for (int ni = 0; ni < 4; ni++) { f32x4 z = {0.f,0.f,0.f,0.f}; O[mi][ni] = z; }
        #pragma unroll
        for (int rr = 0; rr < 4; rr++) { mrun[mi][rr] = -1e30f; lrun[mi][rr] = 0.f; }
    }

    for (int kt6 = 0; kt6 < 6; kt6++) {
        const int kbase = kt6 * 64;
        __syncthreads();
        {
            int key = tid >> 2, kg = tid & 3;
            int gk = kbase + key;
            bf16x8 a0 = bzero8(), a1 = bzero8();
            if (gk < 341) {
                const __hip_bfloat16* src =
                    qkv + (size_t)(b * 341 + gk) * 1536 + 512 + h * 64 + kg * 16;
                a0 = *(const bf16x8*)src;
                a1 = *(const bf16x8*)(src + 8);
            }
            *(bf16x8*)(kt_lds + key * ATT_STR + kg * 16)     = a0;
            *(bf16x8*)(kt_lds + key * ATT_STR + kg * 16 + 8) = a1;
        }
        {
            int key = tid & 63, dg = tid >> 6;
            int gk = kbase + key;
            bf16x8 a0 = bzero8(), a1 = bzero8();
            if (gk < 341) {
                const __hip_bfloat16* src =
                    qkv + (size_t)(b * 341 + gk) * 1536 + 1024 + h * 64 + dg * 16;
                a0 = *(const bf16x8*)src;
                a1 = *(const bf16x8*)(src + 8);
            }
            #pragma unroll
            for (int j = 0; j < 8; j++) {
                vt_lds[(dg * 16 + j) * ATT_STR + key]     = a0[j];
                vt_lds[(dg * 16 + 8 + j) * ATT_STR + key] = a1[j];
            }
        }
        __syncthreads();

        f32x4 S[3][4];
        #pragma unroll
        for (int mi = 0; mi < 3; mi++)
            #pragma unroll
            for (int ni = 0; ni < 4; ni++) { f32x4 z = {0.f,0.f,0.f,0.f}; S[mi][ni] = z; }
        #pragma unroll
        for (int ks = 0; ks < 2; ks++) {
            bf16x8 bf_[4];
            #pragma unroll
            for (int ni = 0; ni < 4; ni++)
                bf_[ni] = *(const bf16x8*)(kt_lds + (ni * 16 + l16) * ATT_STR + ks * 32 + q * 8);
            #pragma unroll
            for (int mi = 0; mi < 3; mi++)
                #pragma unroll
                for (int ni = 0; ni < 4; ni++)
                    S[mi][ni] = __builtin_amdgcn_mfma_f32_16x16x32_bf16(qf[mi][ks], bf_[ni],
                                                                        S[mi][ni], 0, 0, 0);
        }

        float cmask[4];
        #pragma unroll
        for (int ni = 0; ni < 4; ni++)
            cmask[ni] = (kbase + ni * 16 + l16 < 341) ? 0.f : -1e30f;

        #pragma unroll
        for (int mi = 0; mi < 3; mi++) {
            #pragma unroll
            for (int rr = 0; rr < 4; rr++) {
                float rmax = -1e30f;
                #pragma unroll
                for (int ni = 0; ni < 4; ni++)
                    rmax = fmaxf(rmax, fmaf(S[mi][ni][rr], 0.125f, cmask[ni]));
                rmax = fmaxf(rmax, __shfl_xor(rmax, 1));
                rmax = fmaxf(rmax, __shfl_xor(rmax, 2));
                rmax = fmaxf(rmax, __shfl_xor(rmax, 4));
                rmax = fmaxf(rmax, __shfl_xor(rmax, 8));
                float mnew = fmaxf(mrun[mi][rr], rmax);
                float alpha = __expf(mrun[mi][rr] - mnew);
                mrun[mi][rr] = mnew;
                float psum = 0.f;
                #pragma unroll
                for (int ni = 0; ni < 4; ni++) {
                    float p = __expf(fmaf(S[mi][ni][rr], 0.125f, cmask[ni]) - mnew);
                    S[mi][ni][rr] = p;
                    psum += p;
                    O[mi][ni][rr] *= alpha;
                }
                psum += __shfl_xor(psum, 1);
                psum += __shfl_xor(psum, 2);
                psum += __shfl_xor(psum, 4);
                psum += __shfl_xor(psum, 8);
                lrun[mi][rr] = lrun[mi][rr] * alpha + psum;
            }
            #pragma unroll
            for (int ni = 0; ni < 4; ni++)
                #pragma unroll
                for (int rr = 0; rr < 4; rr++)
                    pw[(mi * 16 + q * 4 + rr) * ATT_STR + ni * 16 + l16] =
                        (__bf16)S[mi][ni][rr];
        }
        __syncthreads();

        #pragma unroll
        for (int ks = 0; ks < 2; ks++) {
            bf16x8 pf[3], vf[4];
            #pragma unroll
            for (int mi = 0; mi < 3; mi++)
                pf[mi] = *(const bf16x8*)(pw + (mi * 16 + l16) * ATT_STR + ks * 32 + q * 8);
            #pragma unroll
            for (int ni = 0; ni < 4; ni++)
                vf[ni] = *(const bf16x8*)(vt_lds + (ni * 16 + l16) * ATT_STR + ks * 32 + q * 8);
            #pragma unroll
            for (int mi = 0; mi < 3; mi++)
                #pragma unroll
                for (int ni = 0; ni < 4; ni++)
                    O[mi][ni] = __builtin_amdgcn_mfma_f32_16x16x32_bf16(pf[mi], vf[ni],
                                                                        O[mi][ni], 0, 0, 0);
        }
    }

    #pragma unroll
    for (int mi = 0; mi < 3; mi++) {
        #pragma unroll
        for (int rr = 0; rr < 4; rr++) {
            int row = rowbase + mi * 16 + q * 4 + rr;
            if (row >= 341) continue;
            float inv = 1.f / lrun[mi][rr];
            __hip_bfloat16* op = ctx + (size_t)(b * 341 + row) * 512 + h * 64;
            #pragma unroll
            for (int ni = 0; ni < 4; ni++)
                op[ni * 16 + l16] = __float2bfloat16(O[mi][ni][rr] * inv);
        }
    }
}

// ---------------------------------------------------------------------------
// gemm256 body: C(Mrows,N) = A(Mrows,K) @ Bt(N,K)^T [+bias][+resid][relu]
// 256x256 tile, BK=64, 512 threads = 8 waves (2M x 4N), per-wave C 128x64.
// Schedule per R7 header. Requires K % 64 == 0, K >= 128, N % 256 == 0.
// ---------------------------------------------------------------------------
__device__ __forceinline__ void gload16(const __hip_bfloat16* g, __bf16* l) {
    __builtin_amdgcn_global_load_lds(
        (const __attribute__((address_space(1))) void*)g,
        (__attribute__((address_space(3))) void*)l, 16, 0, 0);
}

#define FULL_BAR() do { asm volatile("" ::: "memory");                        \
    __builtin_amdgcn_sched_barrier(0);                                        \
    __builtin_amdgcn_s_barrier();                                             \
    __builtin_amdgcn_sched_barrier(0); } while (0)

#define LGKM0() do {                                                          \
    asm volatile("s_waitcnt lgkmcnt(0)" ::: "memory");                        \
    __builtin_amdgcn_sched_barrier(0); } while (0)

// stage one half-tile (128 rows x 64 cols bf16): 2 global_load_lds dwordx4
// per wave; LDS dest linear, global source pre-swizzled (slot ^ row&7).
#define STAGE(arr, pr, isB, h, koff) do {                                     \
    __bf16* _d = &smem[((((((pr) << 1) + (isB)) << 1) + (h)) << 13) + w * 1024]; \
    gload16(arr[h][0] + (koff), _d);                                          \
    gload16(arr[h][1] + (koff), _d + 512);                                    \
} while (0)

template <bool GATHER>
static __device__ __forceinline__ void gemm256_body(
    __bf16* smem,
    const __hip_bfloat16* __restrict__ A, const __hip_bfloat16* __restrict__ Bt,
    const float* __restrict__ bias, const float* __restrict__ resid,
    float* __restrict__ Cf, __hip_bfloat16* __restrict__ Cb,
    int Mrows, int N, int K, int flags, int depth, int bm0, int bn0) {
    const int tid = threadIdx.x;
    const int w = tid >> 6, l = tid & 63;
    const int l16 = l & 15, q = l >> 4;
    const int wm = w >> 2, wn = w & 3;
    const int lr8 = l >> 3;               // row within 8-row staging chunk
    const int slog = (l & 7) ^ lr8;       // inverse-swizzled logical 16B slot

    // staging source pointers: [half][j], j = chunk parity within wave
    const __hip_bfloat16* aptr[2][2];
    const __hip_bfloat16* bptr[2][2];
    #pragma unroll
    for (int h = 0; h < 2; h++)
        #pragma unroll
        for (int j = 0; j < 2; j++) {
            int lr = (w * 2 + j) * 8 + lr8;        // local row in half (0..127)
            int grow = bm0 + h * 128 + lr;
            if (grow > Mrows - 1) grow = Mrows - 1;   // clamp; masked at store
            size_t abase;
            if (GATHER) {
                const int dsh = depth << 1;
                const int bmask = (1 << dsh) - 1;
                int bb = grow >> dsh;
                int ii = grow & bmask;
                int node = (0x55555555 & bmask) + ii;
                abase = ((size_t)(bb * 341 + node)) << 9;
            } else {
                abase = (size_t)grow * K;
            }
            aptr[h][j] = A + abase + slog * 8;
            bptr[h][j] = Bt + (size_t)(bn0 + h * 128 + lr) * K + slog * 8;
        }

    // swizzled ds_read slot offsets (elements) for k-slice 0 / 1
    const int sl0 = ((q ^ (l16 & 7)) << 3);
    const int sl1 = (((4 + q) ^ (l16 & 7)) << 3);

    f32x4 acc[8][4];
    #pragma unroll
    for (int i = 0; i < 8; i++)
        #pragma unroll
        for (int j = 0; j < 4; j++) {
            f32x4 z = {0.f, 0.f, 0.f, 0.f};
            acc[i][j] = z;
        }

    // prologue: tile0 (A then B), tile1 (B then A); vmcnt(8) keeps tile1 in flight
    STAGE(aptr, 0, 0, 0, 0);  STAGE(aptr, 0, 0, 1, 0);
    STAGE(bptr, 0, 1, 0, 0);  STAGE(bptr, 0, 1, 1, 0);
    STAGE(bptr, 1, 1, 0, 64); STAGE(bptr, 1, 1, 1, 64);
    STAGE(aptr, 1, 0, 0, 64); STAGE(aptr, 1, 0, 1, 64);
    asm volatile("s_waitcnt vmcnt(8)" ::: "memory");  // tile0 landed; tile1 in flight
    __builtin_amdgcn_sched_barrier(0);
    FULL_BAR();

    const int NT = K >> 6;
    bf16x8 af[4][2], b0[2][2], b1[2][2];

    for (int t = 0; t < NT; ++t) {
        const int p = t & 1;
        const int aro = ((p << 2) + wm) << 13;                         // A half wm
        const int bro = ((((p << 1) + 1) << 1) + (wn >> 1)) * 8192 + ((wn & 1) << 12);

        // ---- phase 1: ds_read A[0..3]x2 + B[0..1]x2 (12)
        #pragma unroll
        for (int mi = 0; mi < 4; mi++) {
            af[mi][0] = *(const bf16x8*)&smem[aro + (mi * 16 + l16) * 64 + sl0];
            af[mi][1] = *(const bf16x8*)&smem[aro + (mi * 16 + l16) * 64 + sl1];
        }
        #pragma unroll
        for (int ni = 0; ni < 2; ni++) {
            b0[ni][0] = *(const bf16x8*)&smem[bro + (ni * 16 + l16) * 64 + sl0];
            b0[ni][1] = *(const bf16x8*)&smem[bro + (ni * 16 + l16) * 64 + sl1];
        }
        FULL_BAR();
        LGKM0();
        __builtin_amdgcn_s_setprio(1);
        #pragma unroll
        for (int ks = 0; ks < 2; ks++)
            #pragma unroll
            for (int mi = 0; mi < 4; mi++)
                #pragma unroll
                for (int ni = 0; ni < 2; ni++)
                    acc[mi][ni] = __builtin_amdgcn_mfma_f32_16x16x32_bf16(
                        af[mi][ks], b0[ni][ks], acc[mi][ni], 0, 0, 0);
        __builtin_amdgcn_s_setprio(0);
        FULL_BAR();

        // ---- phase 2: ds_read B[2..3]x2 (4)
        #pragma unroll
        for (int ni = 0; ni < 2; ni++) {
            b1[ni][0] = *(const bf16x8*)&smem[bro + ((ni + 2) * 16 + l16) * 64 + sl0];
            b1[ni][1] = *(const bf16x8*)&smem[bro + ((ni + 2) * 16 + l16) * 64 + sl1];
        }
        FULL_BAR();
        LGKM0();
        __builtin_amdgcn_s_setprio(1);
        #pragma unroll
        for (int ks = 0; ks < 2; ks++)
            #pragma unroll
            for (int mi = 0; mi < 4; mi++)
                #pragma unroll
                for (int ni = 0; ni < 2; ni++)
                    acc[mi][ni + 2] = __builtin_amdgcn_mfma_f32_16x16x32_bf16(
                        af[mi][ks], b1[ni][ks], acc[mi][ni + 2], 0, 0, 0);
        __builtin_amdgcn_s_setprio(0);
        FULL_BAR();

        // ---- phase 3: ds_read A[4..7]x2 (8); STAGE B-half0(t+2) -> buffer p
        //      (B region of p last read in ph2, drained by ph2's LGKM0+bar)
        #pragma unroll
        for (int mi = 0; mi < 4; mi++) {
            af[mi][0] = *(const bf16x8*)&smem[aro + ((mi + 4) * 16 + l16) * 64 + sl0];
            af[mi][1] = *(const bf16x8*)&smem[aro + ((mi + 4) * 16 + l16) * 64 + sl1];
        }
        if (t + 2 < NT) STAGE(bptr, p, 1, 0, (t + 2) << 6);
        FULL_BAR();
        LGKM0();
        __builtin_amdgcn_s_setprio(1);
        #pragma unroll
        for (int ks = 0; ks < 2; ks++)
            #pragma unroll
            for (int mi = 0; mi < 4; mi++)
                #pragma unroll
                for (int ni = 0; ni < 2; ni++)
                    acc[mi + 4][ni + 2] = __builtin_amdgcn_mfma_f32_16x16x32_bf16(
                        af[mi][ks], b1[ni][ks], acc[mi + 4][ni + 2], 0, 0, 0);
        __builtin_amdgcn_s_setprio(0);
        FULL_BAR();

        // ---- phase 4: STAGE B-h1 + A-h0 + A-h1 (t+2) -> buffer p; MFMA;
        //      counted vmcnt(8): drain tile t+1, keep tile t+2 in flight.
        if (t + 2 < NT) {
            STAGE(bptr, p, 1, 1, (t + 2) << 6);
            STAGE(aptr, p, 0, 0, (t + 2) << 6);
            STAGE(aptr, p, 0, 1, (t + 2) << 6);
        }
        __builtin_amdgcn_s_setprio(1);
        #pragma unroll
        for (int ks = 0; ks < 2; ks++)
            #pragma unroll
            for (int mi = 0; mi < 4; mi++)
                #pragma unroll
                for (int ni = 0; ni < 2; ni++)
                    acc[mi + 4][ni] = __builtin_amdgcn_mfma_f32_16x16x32_bf16(
                        af[mi][ks], b0[ni][ks], acc[mi + 4][ni], 0, 0, 0);
        __builtin_amdgcn_s_setprio(0);
        if (t + 1 < NT) {
            if (t + 2 < NT) { asm volatile("s_waitcnt vmcnt(8)" ::: "memory"); }
            else            { asm volatile("s_waitcnt vmcnt(0)" ::: "memory"); }
            __builtin_amdgcn_sched_barrier(0);
        }
        FULL_BAR();
    }

    // epilogue
    #pragma unroll
    for (int mi = 0; mi < 8; mi++) {
        #pragma unroll
        for (int rr2 = 0; rr2 < 4; rr2++) {
            int grow = bm0 + wm * 128 + mi * 16 + q * 4 + rr2;
            if (grow >= Mrows) continue;
            size_t obase = (size_t)grow * N;
            #pragma unroll
            for (int ni = 0; ni < 4; ni++) {
                int col = bn0 + wn * 64 + ni * 16 + l16;
                float v = acc[mi][ni][rr2];
                if (bias) v += bias[col];
                if (resid) v += resid[obase + col];
                if (flags & GF_RELU) v = fmaxf(v, 0.f);
                if (flags & GF_OUTBF16)
                    Cb[obase + col] = __float2bfloat16(v);
                else
                    Cf[obase + col] = v;
            }
        }
    }
}

// bijective XCD-aware remap (m204): contiguous logical chunks per XCD.
static __device__ __forceinline__ int xcd_remap(int bid, int nwg) {
    const int xcd = bid & 7, o = bid >> 3;
    const int qq = nwg >> 3, rr = nwg & 7;
    return (xcd < rr ? xcd * (qq + 1) : rr * (qq + 1) + (xcd - rr) * qq) + o;
}

template <bool GATHER>
__global__ __launch_bounds__(512, 2) void gemm256(
    const __hip_bfloat16* __restrict__ A, const __hip_bfloat16* __restrict__ Bt,
    const float* __restrict__ bias, const float* __restrict__ resid,
    float* __restrict__ Cf, __hip_bfloat16* __restrict__ Cb,
    int Mrows, int N, int K, int flags, int depth, int gridN) {
    __shared__ __align__(128) __bf16 smem[65536];  // 128 KiB
    const int lin = xcd_remap(blockIdx.x, gridDim.x);
    const int bx = lin / gridN;
    const int by = lin - bx * gridN;
    gemm256_body<GATHER>(smem, A, Bt, bias, resid, Cf, Cb,
                         Mrows, N, K, flags, depth, bx << 8, by << 8);
}

// ---------------------------------------------------------------------------
// Fused branch-MLP GEMM: all 5 source-depth levels in ONE 936-block dispatch
// (s=0: 1x40, s=1: 1x32, s=2: 4x24, s=3: 16x16, s=4: 64x8 blocks; all
// K=512, 256^2 tiles -> identical per-block work, no serial tails).
// ---------------------------------------------------------------------------
__global__ __launch_bounds__(512, 2) void gemm_branch_fused(
    const __hip_bfloat16* __restrict__ xn, const __hip_bfloat16* __restrict__ wcat,
    __hip_bfloat16* __restrict__ Y) {
    __shared__ __align__(128) __bf16 smem[65536];
    const int lin = xcd_remap(blockIdx.x, gridDim.x);
    int s;
    if (lin < 40)       s = 0;
    else if (lin < 72)  s = 1;
    else if (lin < 168) s = 2;
    else if (lin < 424) s = 3;
    else                s = 4;
    const int base_tab[5] = {0, 40, 72, 168, 424};
    const int gn_tab[5]   = {40, 32, 24, 16, 8};
    const size_t yoff[5]  = {0, 655360, 2752512, 9043968, 25821184};
    const int wcat_off[5] = {0, 5, 9, 12, 14};
    const int loc = lin - base_tab[s];
    const int gn = gn_tab[s];
    const int bx = loc / gn;
    const int by = loc - bx * gn;
    const int Mrows = 64 << (s << 1);
    const int N = (5 - s) << 11;
    gemm256_body<true>(smem, xn, wcat + (size_t)wcat_off[s] * (2048ull * 512),
                       nullptr, nullptr, nullptr, Y + yoff[s],
                       Mrows, N, 512, GF_OUTBF16, s, bx << 8, by << 8);
}

// ---------------------------------------------------------------------------
// Combine: h[b,node@d,:] = ReLU( sum_{s<=d} Y_s[...] + b1[node] )  (unchanged)
// ---------------------------------------------------------------------------
__global__ __launch_bounds__(256) void combine_kernel(const __hip_bfloat16* __restrict__ Y,
                                                      const float* __restrict__ b1,
                                                      __hip_bfloat16* __restrict__ h) {
    const size_t yoff[5] = {0, 655360, 2752512, 9043968, 25821184};
    int row = blockIdx.x;
    int b = row / 341;
    int node = row - b * 341;
    int d = (node >= 85) ? 4 : (node >= 21) ? 3 : (node >= 5) ? 2 : (node >= 1) ? 1 : 0;
    int i = node - (0x55555555 & ((1 << (d << 1)) - 1));
    int j = threadIdx.x << 3;

    float acc[8];
    const float* bp = b1 + (size_t)node * 2048 + j;
    f32x4 b0 = *(const f32x4*)bp;
    f32x4 b4 = *(const f32x4*)(bp + 4);
    #pragma unroll
    for (int u = 0; u < 4; u++) { acc[u] = b0[u]; acc[u + 4] = b4[u]; }

    #pragma unroll
    for (int s = 0; s < 5; s++) {
        if (s <= d) {
            int a = i >> ((d - s) << 1);
            int width = (5 - s) << 11;
            const bf16x8 v = *(const bf16x8*)(Y + yoff[s] +
                (size_t)((b << (s << 1)) + a) * width + ((d - s) << 11) + j);
            #pragma unroll
            for (int u = 0; u < 8; u++) acc[u] += (float)v[u];
        }
    }
    bf16x8 o;
    #pragma unroll
    for (int u = 0; u < 8; u++) o[u] = (__bf16)fmaxf(acc[u], 0.f);
    *(bf16x8*)(h + (size_t)row * 2048 + j) = o;
}

// ---------------------------------------------------------------------------
extern "C" void kernel_launch(void* const* d_in, const int* in_sizes, int n_in,
                              void* d_out, int out_size, void* d_ws, size_t ws_size,
                              hipStream_t stream) {
    const float* x      = (const float*)d_in[0];
    const float* ln1_g  = (const float*)d_in[1];
    const float* ln1_b  = (const float*)d_in[2];
    const float* w_qkv  = (const float*)d_in[3];
    const float* b_qkv  = (const float*)d_in[4];
    const float* w_proj = (const float*)d_in[5];
    const float* b_proj = (const float*)d_in[6];
    const float* ln2_g  = (const float*)d_in[7];
    const float* ln2_b  = (const float*)d_in[8];
    const float* mlp_M  = (const float*)d_in[9];
    const float* mlp_b1 = (const float*)d_in[10];
    const float* w2     = (const float*)d_in[11];
    const float* b2     = (const float*)d_in[12];
    float* out = (float*)d_out;

    const int M = 64 * 341;  // 21824 rows

    char* ws = (char*)d_ws;
    size_t off = 0;
    auto alloc = [&](size_t bytes) -> char* {
        char* p = ws + off;
        off += (bytes + 255) & ~(size_t)255;
        return p;
    };
    __hip_bfloat16* xn     = (__hip_bfloat16*)alloc((size_t)M * 512 * 2);
    __hip_bfloat16* wqkvT  = (__hip_bfloat16*)alloc(1536ull * 512 * 2);
    __hip_bfloat16* wprojT = (__hip_bfloat16*)alloc(512ull * 512 * 2);
    __hip_bfloat16* w2T    = (__hip_bfloat16*)alloc(512ull * 2048 * 2);
    __hip_bfloat16* wcat   = (__hip_bfloat16*)alloc(15ull * 2048 * 512 * 2);
    __hip_bfloat16* hbuf   = (__hip_bfloat16*)alloc((size_t)M * 2048 * 2);
    // shared region: qkv+ctx (attention phase) overlaid by Y (branch phase)
    const size_t qkv_bytes = (size_t)M * 1536 * 2;            // 67,043,328
    const size_t y_bytes   = 59375616ull * 2;                 // 118,751,232
    char* shared = alloc(y_bytes);                            // >= qkv+ctx
    __hip_bfloat16* qkv = (__hip_bfloat16*)shared;
    __hip_bfloat16* ctx = (__hip_bfloat16*)(shared + qkv_bytes);
    __hip_bfloat16* Y   = (__hip_bfloat16*)shared;
    if (off > ws_size) return;  // workspace too small -> clean validation failure

    auto g256 = [&](const __hip_bfloat16* A, const __hip_bfloat16* Bt,
                    const float* bias, const float* resid, float* Cf,
                    __hip_bfloat16* Cb, int Mr, int N, int K, int flags) {
        int gm = (Mr + 255) >> 8, gn = N >> 8;
        gemm256<false><<<dim3(gm * gn), 512, 0, stream>>>(
            A, Bt, bias, resid, Cf, Cb, Mr, N, K, flags, 0, gn);
    };

    // weight prep
    transpose_bf16_kernel<<<(512 * 1536 + 255) / 256, 256, 0, stream>>>(w_qkv, wqkvT, 512, 1536, 9);
    transpose_bf16_kernel<<<(512 * 512 + 255) / 256, 256, 0, stream>>>(w_proj, wprojT, 512, 512, 9);
    transpose_bf16_kernel<<<(2048 * 512 + 255) / 256, 256, 0, stream>>>(w2, w2T, 2048, 512, 11);
    pack_wcat_kernel<<<dim3(4096, 15), 256, 0, stream>>>(mlp_M, wcat);

    // attention path
    ln_kernel<<<M, 256, 0, stream>>>(x, ln1_g, ln1_b, xn);
    g256(xn, wqkvT, b_qkv, nullptr, nullptr, qkv, M, 1536, 512, GF_OUTBF16);
    attn_mfma_kernel<<<dim3(512, 2), 256, 0, stream>>>(qkv, ctx);
    g256(ctx, wprojT, b_proj, x, out, nullptr, M, 512, 512, 0);

    // branch MLP path (dedup by source depth s) — single fused dispatch
    ln_kernel<<<M, 256, 0, stream>>>(out, ln2_g, ln2_b, xn);
    gemm_branch_fused<<<dim3(936), 512, 0, stream>>>(xn, wcat, Y);
    combine_kernel<<<M, 256, 0, stream>>>(Y, mlp_b1, hbuf);
    g256(hbuf, w2T, b2, out, out, nullptr, M, 512, 2048, 0);
}

// Round 3
// 785.299 us; speedup vs baseline: 1.1698x; 1.0753x over previous
//
#include <hip/hip_runtime.h>
#include <hip/hip_bf16.h>

// ---------------------------------------------------------------------------
// Treensformer block: x += MHSA(LN1(x)); x += BranchMLP(LN2(x))
// B=64, N_NODES=341, E=512, H=8, hd=64, 4*E=2048, N_LEVELS=4
// R1: MFMA flash attention. R5: branch-MLP ancestor dedup (Y_s by source
//     depth s; combine kernel). R5 GEMM: 128x128xBK32 register-staged,
//     2 syncthreads/step, ~2.7 blocks/CU implicit overlap (w2 = 144us).
// R6/R7: 256x256xBK64 deep-pipelined gemm256 (glds + counted vmcnt +
//     raw barriers). RESULT: w2 164-166us, MfmaUtil ~10.7 REGARDLESS of
//     prefetch depth (R6 ~2.5-phase vs R7 full-iteration distance ->
//     identical) -> stall is not vmcnt position; the 1-block/CU lockstep
//     structure bottoms out ~4x slower per K-tile than the reference
//     m201 kernel. Also: N=512 GEMMs (proj/w2) have only 172 tiles at
//     256^2 -> cannot fill 256 CUs, ever. 256^2 is shape-wrong here.
//     KEPT from R7: fused branch dispatch (918 -> 844, ~74us).
// R8: consolidate to measured-best: R5 128^2 body for ALL GEMMs +
//     fused branch at 128^2 tiles (3664 blocks) + bijective XCD remap
//     with A-major linear ordering (addressing-only; targets R5's 2.4x
//     A refetch: FETCH 216MB vs A=89MB on w2). Bank-conflict swizzle
//     deliberately NOT added (T2 null on 2-phase structures per the
//     regime-gate evidence).
// ---------------------------------------------------------------------------

typedef __attribute__((ext_vector_type(8))) __bf16 bf16x8;
typedef __attribute__((ext_vector_type(4))) float f32x4;
typedef __attribute__((ext_vector_type(4))) unsigned int u32x4;

#define GF_RELU    1
#define GF_OUTBF16 2

static __device__ __forceinline__ bf16x8 bzero8() {
    u32x4 z = {0u, 0u, 0u, 0u};
    return __builtin_bit_cast(bf16x8, z);
}

// ---------------------------------------------------------------------------
// Weight transpose+convert: out[n*K + k] = bf16(in[k*N + n]); K is pow2.
// ---------------------------------------------------------------------------
__global__ void transpose_bf16_kernel(const float* __restrict__ in,
                                      __hip_bfloat16* __restrict__ out,
                                      int K, int N, int log2K) {
    int idx = blockIdx.x * 256 + threadIdx.x;
    if (idx >= K * N) return;
    int n = idx >> log2K;
    int k = idx & (K - 1);
    out[idx] = __float2bfloat16(in[(size_t)k * N + n]);
}

// ---------------------------------------------------------------------------
// Pack mlp_M (5,5,2048,512) fp32 -> Wcat bf16 grouped by source depth s.
// ---------------------------------------------------------------------------
__global__ void pack_wcat_kernel(const float* __restrict__ M,
                                 __hip_bfloat16* __restrict__ out) {
    int p = blockIdx.y;
    int s, d;
    if (p < 5)       { s = 0; d = p; }
    else if (p < 9)  { s = 1; d = p - 4; }
    else if (p < 12) { s = 2; d = p - 7; }
    else if (p < 14) { s = 3; d = p - 9; }
    else             { s = 4; d = 4; }
    const int base_lut[5] = {0, 5, 9, 12, 14};
    size_t idx = (size_t)blockIdx.x * 256 + threadIdx.x;  // 0 .. 2048*512-1
    const size_t MB = 2048ull * 512;
    out[(size_t)base_lut[s] * MB + (size_t)(d - s) * MB + idx] =
        __float2bfloat16(M[((size_t)d * 5 + s) * MB + idx]);
}

// ---------------------------------------------------------------------------
// LayerNorm over E=512, one block (256 threads) per token; writes bf16.
// ---------------------------------------------------------------------------
__global__ __launch_bounds__(256) void ln_kernel(const float* __restrict__ x,
                                                 const float* __restrict__ g,
                                                 const float* __restrict__ b,
                                                 __hip_bfloat16* __restrict__ out) {
    int tok = blockIdx.x;
    const float* xr = x + (size_t)tok * 512;
    int t = threadIdx.x;
    float v0 = xr[t], v1 = xr[t + 256];
    float s = v0 + v1;
    float s2 = v0 * v0 + v1 * v1;
    #pragma unroll
    for (int o = 32; o > 0; o >>= 1) {
        s  += __shfl_down(s, o);
        s2 += __shfl_down(s2, o);
    }
    __shared__ float ps[4], ps2[4];
    int w = t >> 6, lane = t & 63;
    if (lane == 0) { ps[w] = s; ps2[w] = s2; }
    __syncthreads();
    if (t == 0) {
        float ts = 0.f, ts2 = 0.f;
        #pragma unroll
        for (int i = 0; i < 4; i++) { ts += ps[i]; ts2 += ps2[i]; }
        ps[0] = ts * (1.f / 512.f);
        ps2[0] = ts2 * (1.f / 512.f);
    }
    __syncthreads();
    float m = ps[0];
    float var = ps2[0] - m * m;
    float r = rsqrtf(var + 1e-5f);
    out[(size_t)tok * 512 + t]       = __float2bfloat16((v0 - m) * r * g[t] + b[t]);
    out[(size_t)tok * 512 + t + 256] = __float2bfloat16((v1 - m) * r * g[t + 256] + b[t + 256]);
}

// ---------------------------------------------------------------------------
// MFMA flash attention (unchanged from R2).
// ---------------------------------------------------------------------------
#define ATT_STR 72
__global__ __launch_bounds__(256) void attn_mfma_kernel(const __hip_bfloat16* __restrict__ qkv,
                                                        __hip_bfloat16* __restrict__ ctx) {
    __shared__ __bf16 kt_lds[64 * ATT_STR];
    __shared__ __bf16 vt_lds[64 * ATT_STR];
    __shared__ __bf16 pbuf[4 * 48 * ATT_STR];

    const int bh = blockIdx.x;
    const int half = blockIdx.y;
    const int b = bh >> 3, h = bh & 7;
    const int tid = threadIdx.x;
    const int w = tid >> 6, lane = tid & 63;
    const int q = lane >> 4, l16 = lane & 15;
    const int rowbase = half * 192 + w * 48;
    __bf16* pw = pbuf + w * 48 * ATT_STR;

    bf16x8 qf[3][2];
    #pragma unroll
    for (int mi = 0; mi < 3; mi++) {
        int row = rowbase + mi * 16 + l16;
        #pragma unroll
        for (int ks = 0; ks < 2; ks++) {
            if (row < 341)
                qf[mi][ks] = *(const bf16x8*)(qkv + (size_t)(b * 341 + row) * 1536 +
                                              h * 64 + ks * 32 + q * 8);
            else
                qf[mi][ks] = bzero8();
        }
    }

    f32x4 O[3][4];
    float mrun[3][4], lrun[3][4];
    #pragma unroll
    for (int mi = 0; mi < 3; mi++) {
        #pragma unroll
        for (int ni = 0; ni < 4; ni++) { f32x4 z = {0.f,0.f,0.f,0.f}; O[mi][ni] = z; }
        #pragma unroll
        for (int rr = 0; rr < 4; rr++) { mrun[mi][rr] = -1e30f; lrun[mi][rr] = 0.f; }
    }

    for (int kt6 = 0; kt6 < 6; kt6++) {
        const int kbase = kt6 * 64;
        __syncthreads();
        {
            int key = tid >> 2, kg = tid & 3;
            int gk = kbase + key;
            bf16x8 a0 = bzero8(), a1 = bzero8();
            if (gk < 341) {
                const __hip_bfloat16* src =
                    qkv + (size_t)(b * 341 + gk) * 1536 + 512 + h * 64 + kg * 16;
                a0 = *(const bf16x8*)src;
                a1 = *(const bf16x8*)(src + 8);
            }
            *(bf16x8*)(kt_lds + key * ATT_STR + kg * 16)     = a0;
            *(bf16x8*)(kt_lds + key * ATT_STR + kg * 16 + 8) = a1;
        }
        {
            int key = tid & 63, dg = tid >> 6;
            int gk = kbase + key;
            bf16x8 a0 = bzero8(), a1 = bzero8();
            if (gk < 341) {
                const __hip_bfloat16* src =
                    qkv + (size_t)(b * 341 + gk) * 1536 + 1024 + h * 64 + dg * 16;
                a0 = *(const bf16x8*)src;
                a1 = *(const bf16x8*)(src + 8);
            }
            #pragma unroll
            for (int j = 0; j < 8; j++) {
                vt_lds[(dg * 16 + j) * ATT_STR + key]     = a0[j];
                vt_lds[(dg * 16 + 8 + j) * ATT_STR + key] = a1[j];
            }
        }
        __syncthreads();

        f32x4 S[3][4];
        #pragma unroll
        for (int mi = 0; mi < 3; mi++)
            #pragma unroll
            for (int ni = 0; ni < 4; ni++) { f32x4 z = {0.f,0.f,0.f,0.f}; S[mi][ni] = z; }
        #pragma unroll
        for (int ks = 0; ks < 2; ks++) {
            bf16x8 bf_[4];
            #pragma unroll
            for (int ni = 0; ni < 4; ni++)
                bf_[ni] = *(const bf16x8*)(kt_lds + (ni * 16 + l16) * ATT_STR + ks * 32 + q * 8);
            #pragma unroll
            for (int mi = 0; mi < 3; mi++)
                #pragma unroll
                for (int ni = 0; ni < 4; ni++)
                    S[mi][ni] = __builtin_amdgcn_mfma_f32_16x16x32_bf16(qf[mi][ks], bf_[ni],
                                                                        S[mi][ni], 0, 0, 0);
        }

        float cmask[4];
        #pragma unroll
        for (int ni = 0; ni < 4; ni++)
            cmask[ni] = (kbase + ni * 16 + l16 < 341) ? 0.f : -1e30f;

        #pragma unroll
        for (int mi = 0; mi < 3; mi++) {
            #pragma unroll
            for (int rr = 0; rr < 4; rr++) {
                float rmax = -1e30f;
                #pragma unroll
                for (int ni = 0; ni < 4; ni++)
                    rmax = fmaxf(rmax, fmaf(S[mi][ni][rr], 0.125f, cmask[ni]));
                rmax = fmaxf(rmax, __shfl_xor(rmax, 1));
                rmax = fmaxf(rmax, __shfl_xor(rmax, 2));
                rmax = fmaxf(rmax, __shfl_xor(rmax, 4));
                rmax = fmaxf(rmax, __shfl_xor(rmax, 8));
                float mnew = fmaxf(mrun[mi][rr], rmax);
                float alpha = __expf(mrun[mi][rr] - mnew);
                mrun[mi][rr] = mnew;
                float psum = 0.f;
                #pragma unroll
                for (int ni = 0; ni < 4; ni++) {
                    float p = __expf(fmaf(S[mi][ni][rr], 0.125f, cmask[ni]) - mnew);
                    S[mi][ni][rr] = p;
                    psum += p;
                    O[mi][ni][rr] *= alpha;
                }
                psum += __shfl_xor(psum, 1);
                psum += __shfl_xor(psum, 2);
                psum += __shfl_xor(psum, 4);
                psum += __shfl_xor(psum, 8);
                lrun[mi][rr] = lrun[mi][rr] * alpha + psum;
            }
            #pragma unroll
            for (int ni = 0; ni < 4; ni++)
                #pragma unroll
                for (int rr = 0; rr < 4; rr++)
                    pw[(mi * 16 + q * 4 + rr) * ATT_STR + ni * 16 + l16] =
                        (__bf16)S[mi][ni][rr];
        }
        __syncthreads();

        #pragma unroll
        for (int ks = 0; ks < 2; ks++) {
            bf16x8 pf[3], vf[4];
            #pragma unroll
            for (int mi = 0; mi < 3; mi++)
                pf[mi] = *(const bf16x8*)(pw + (mi * 16 + l16) * ATT_STR + ks * 32 + q * 8);
            #pragma unroll
            for (int ni = 0; ni < 4; ni++)
                vf[ni] = *(const bf16x8*)(vt_lds + (ni * 16 + l16) * ATT_STR + ks * 32 + q * 8);
            #pragma unroll
            for (int mi = 0; mi < 3; mi++)
                #pragma unroll
                for (int ni = 0; ni < 4; ni++)
                    O[mi][ni] = __builtin_amdgcn_mfma_f32_16x16x32_bf16(pf[mi], vf[ni],
                                                                        O[mi][ni], 0, 0, 0);
        }
    }

    #pragma unroll
    for (int mi = 0; mi < 3; mi++) {
        #pragma unroll
        for (int rr = 0; rr < 4; rr++) {
            int row = rowbase + mi * 16 + q * 4 + rr;
            if (row >= 341) continue;
            float inv = 1.f / lrun[mi][rr];
            __hip_bfloat16* op = ctx + (size_t)(b * 341 + row) * 512 + h * 64;
            #pragma unroll
            for (int ni = 0; ni < 4; ni++)
                op[ni * 16 + l16] = __float2bfloat16(O[mi][ni][rr] * inv);
        }
    }
}

// ---------------------------------------------------------------------------
// R5 GEMM body: C(Mrows,N) = A(Mrows,K) @ Bt(N,K)^T [+bias][+resid][relu]
// Tile 128x128xBK32, 256 threads = 4 waves (2x2 of 64x64). Register staging
// (global->VGPR loads hoist above the tile barrier = implicit prefetch;
// proven best: w2 = 144us vs 164-166us for the 256^2 deep pipeline).
// GATHER=true (self-gather): A row gr -> b = gr>>2s, i = gr & (4^s-1),
// node = offs[s]+i with offs[s] = 0x55555555 & mask; A row = xn[b*341+node].
// Output rows linear (Y_s layout). K=512 in gather mode.
// ---------------------------------------------------------------------------
template <bool GATHER>
static __device__ __forceinline__ void gemm128_body(
    __hip_bfloat16* As, __hip_bfloat16* Bs,
    const __hip_bfloat16* __restrict__ A, const __hip_bfloat16* __restrict__ Bt,
    const float* __restrict__ bias, const float* __restrict__ resid,
    float* __restrict__ Cf, __hip_bfloat16* __restrict__ Cb,
    int Mrows, int N, int K, int flags, int depth, int bm0, int bn0) {
    const int tid = threadIdx.x;
    const int r = tid >> 1;            // staging row 0..127
    const int kh = (tid & 1) << 4;     // 0 / 16
    const int gr = bm0 + r;
    const int gn = bn0 + r;
    const int lane = tid & 63;
    const int w = tid >> 6;
    const int wm = (w >> 1) << 6;
    const int wn = (w & 1) << 6;
    const int q = lane >> 4;
    const int l16 = lane & 15;

    size_t abase;
    if (GATHER) {
        const int dsh = depth << 1;
        const int bmask = (1 << dsh) - 1;
        int b = gr >> dsh;
        int i = gr & bmask;
        int node = (0x55555555 & bmask) + i;   // offs[depth] + i
        abase = ((size_t)(b * 341 + node)) << 9;
    } else {
        abase = (size_t)gr * K;
    }

    f32x4 acc[4][4];
    #pragma unroll
    for (int i = 0; i < 4; i++)
        #pragma unroll
        for (int j = 0; j < 4; j++) {
            f32x4 z = {0.f, 0.f, 0.f, 0.f};
            acc[i][j] = z;
        }

    for (int k0 = 0; k0 < K; k0 += 32) {
        bf16x8 va0 = bzero8(), va1 = bzero8(), vb0, vb1;
        if (gr < Mrows) {
            const bf16x8* p = (const bf16x8*)(A + abase + k0 + kh);
            va0 = p[0];
            va1 = p[1];
        }
        {
            const bf16x8* p = (const bf16x8*)(Bt + (size_t)gn * K + k0 + kh);
            vb0 = p[0];
            vb1 = p[1];
        }
        __syncthreads();  // previous iteration's fragment reads complete
        *(bf16x8*)(As + r * 32 + kh)     = va0;
        *(bf16x8*)(As + r * 32 + kh + 8) = va1;
        *(bf16x8*)(Bs + r * 32 + kh)     = vb0;
        *(bf16x8*)(Bs + r * 32 + kh + 8) = vb1;
        __syncthreads();
        bf16x8 af[4], bfr[4];
        #pragma unroll
        for (int mi = 0; mi < 4; mi++)
            af[mi] = *(const bf16x8*)(As + (wm + mi * 16 + l16) * 32 + q * 8);
        #pragma unroll
        for (int ni = 0; ni < 4; ni++)
            bfr[ni] = *(const bf16x8*)(Bs + (wn + ni * 16 + l16) * 32 + q * 8);
        #pragma unroll
        for (int mi = 0; mi < 4; mi++)
            #pragma unroll
            for (int ni = 0; ni < 4; ni++)
                acc[mi][ni] = __builtin_amdgcn_mfma_f32_16x16x32_bf16(
                    af[mi], bfr[ni], acc[mi][ni], 0, 0, 0);
    }

    #pragma unroll
    for (int mi = 0; mi < 4; mi++) {
        #pragma unroll
        for (int rr = 0; rr < 4; rr++) {
            int grow = bm0 + wm + mi * 16 + q * 4 + rr;
            if (grow >= Mrows) continue;
            size_t obase = (size_t)grow * N;
            #pragma unroll
            for (int ni = 0; ni < 4; ni++) {
                int col = bn0 + wn + ni * 16 + l16;
                float v = acc[mi][ni][rr];
                if (bias) v += bias[col];
                if (resid) v += resid[obase + col];
                if (flags & GF_RELU) v = fmaxf(v, 0.f);
                if (flags & GF_OUTBF16)
                    Cb[obase + col] = __float2bfloat16(v);
                else
                    Cf[obase + col] = v;
            }
        }
    }
}

// bijective XCD-aware remap (m204): each XCD gets a contiguous chunk of the
// logical (A-major) tile order -> neighboring tiles sharing an A row-panel
// land on the same XCD's L2.
static __device__ __forceinline__ int xcd_remap(int bid, int nwg) {
    const int xcd = bid & 7, o = bid >> 3;
    const int qq = nwg >> 3, rr = nwg & 7;
    return (xcd < rr ? xcd * (qq + 1) : rr * (qq + 1) + (xcd - rr) * qq) + o;
}

__global__ __launch_bounds__(256) void gemm128(
    const __hip_bfloat16* __restrict__ A, const __hip_bfloat16* __restrict__ Bt,
    const float* __restrict__ bias, const float* __restrict__ resid,
    float* __restrict__ Cf, __hip_bfloat16* __restrict__ Cb,
    int Mrows, int N, int K, int flags, int gridN) {
    __shared__ __hip_bfloat16 As[128 * 32];
    __shared__ __hip_bfloat16 Bs[128 * 32];
    const int lin = xcd_remap(blockIdx.x, gridDim.x);
    const int bx = lin / gridN;           // A-major: consecutive lin share A panel
    const int by = lin - bx * gridN;
    gemm128_body<false>(As, Bs, A, Bt, bias, resid, Cf, Cb,
                        Mrows, N, K, flags, 0, bx << 7, by << 7);
}

// ---------------------------------------------------------------------------
// Fused branch-MLP GEMM: all 5 source-depth levels in ONE 3664-block
// dispatch at 128^2 tiles (s=0: 1x80, s=1: 2x64, s=2: 8x48, s=3: 32x32,
// s=4: 128x16). K=512 for all -> identical per-block work, no serial tails.
// ---------------------------------------------------------------------------
__global__ __launch_bounds__(256) void gemm_branch_fused(
    const __hip_bfloat16* __restrict__ xn, const __hip_bfloat16* __restrict__ wcat,
    __hip_bfloat16* __restrict__ Y) {
    __shared__ __hip_bfloat16 As[128 * 32];
    __shared__ __hip_bfloat16 Bs[128 * 32];
    const int lin = xcd_remap(blockIdx.x, gridDim.x);
    int s;
    if (lin < 80)        s = 0;
    else if (lin < 208)  s = 1;
    else if (lin < 592)  s = 2;
    else if (lin < 1616) s = 3;
    else                 s = 4;
    const int base_tab[5] = {0, 80, 208, 592, 1616};
    const int gn_tab[5]   = {80, 64, 48, 32, 16};
    const size_t yoff[5]  = {0, 655360, 2752512, 9043968, 25821184};
    const int wcat_off[5] = {0, 5, 9, 12, 14};
    const int loc = lin - base_tab[s];
    const int gn = gn_tab[s];
    const int bx = loc / gn;              // A-major within each s
    const int by = loc - bx * gn;
    const int Mrows = 64 << (s << 1);
    const int N = (5 - s) << 11;
    gemm128_body<true>(As, Bs, xn, wcat + (size_t)wcat_off[s] * (2048ull * 512),
                       nullptr, nullptr, nullptr, Y + yoff[s],
                       Mrows, N, 512, GF_OUTBF16, s, bx << 7, by << 7);
}

// ---------------------------------------------------------------------------
// Combine: h[b,node@d,:] = ReLU( sum_{s<=d} Y_s[...] + b1[node] )  (unchanged)
// ---------------------------------------------------------------------------
__global__ __launch_bounds__(256) void combine_kernel(const __hip_bfloat16* __restrict__ Y,
                                                      const float* __restrict__ b1,
                                                      __hip_bfloat16* __restrict__ h) {
    const size_t yoff[5] = {0, 655360, 2752512, 9043968, 25821184};
    int row = blockIdx.x;
    int b = row / 341;
    int node = row - b * 341;
    int d = (node >= 85) ? 4 : (node >= 21) ? 3 : (node >= 5) ? 2 : (node >= 1) ? 1 : 0;
    int i = node - (0x55555555 & ((1 << (d << 1)) - 1));
    int j = threadIdx.x << 3;

    float acc[8];
    const float* bp = b1 + (size_t)node * 2048 + j;
    f32x4 b0 = *(const f32x4*)bp;
    f32x4 b4 = *(const f32x4*)(bp + 4);
    #pragma unroll
    for (int u = 0; u < 4; u++) { acc[u] = b0[u]; acc[u + 4] = b4[u]; }

    #pragma unroll
    for (int s = 0; s < 5; s++) {
        if (s <= d) {
            int a = i >> ((d - s) << 1);
            int width = (5 - s) << 11;
            const bf16x8 v = *(const bf16x8*)(Y + yoff[s] +
                (size_t)((b << (s << 1)) + a) * width + ((d - s) << 11) + j);
            #pragma unroll
            for (int u = 0; u < 8; u++) acc[u] += (float)v[u];
        }
    }
    bf16x8 o;
    #pragma unroll
    for (int u = 0; u < 8; u++) o[u] = (__bf16)fmaxf(acc[u], 0.f);
    *(bf16x8*)(h + (size_t)row * 2048 + j) = o;
}

// ---------------------------------------------------------------------------
extern "C" void kernel_launch(void* const* d_in, const int* in_sizes, int n_in,
                              void* d_out, int out_size, void* d_ws, size_t ws_size,
                              hipStream_t stream) {
    const float* x      = (const float*)d_in[0];
    const float* ln1_g  = (const float*)d_in[1];
    const float* ln1_b  = (const float*)d_in[2];
    const float* w_qkv  = (const float*)d_in[3];
    const float* b_qkv  = (const float*)d_in[4];
    const float* w_proj = (const float*)d_in[5];
    const float* b_proj = (const float*)d_in[6];
    const float* ln2_g  = (const float*)d_in[7];
    const float* ln2_b  = (const float*)d_in[8];
    const float* mlp_M  = (const float*)d_in[9];
    const float* mlp_b1 = (const float*)d_in[10];
    const float* w2     = (const float*)d_in[11];
    const float* b2     = (const float*)d_in[12];
    float* out = (float*)d_out;

    const int M = 64 * 341;  // 21824 rows

    char* ws = (char*)d_ws;
    size_t off = 0;
    auto alloc = [&](size_t bytes) -> char* {
        char* p = ws + off;
        off += (bytes + 255) & ~(size_t)255;
        return p;
    };
    __hip_bfloat16* xn     = (__hip_bfloat16*)alloc((size_t)M * 512 * 2);
    __hip_bfloat16* wqkvT  = (__hip_bfloat16*)alloc(1536ull * 512 * 2);
    __hip_bfloat16* wprojT = (__hip_bfloat16*)alloc(512ull * 512 * 2);
    __hip_bfloat16* w2T    = (__hip_bfloat16*)alloc(512ull * 2048 * 2);
    __hip_bfloat16* wcat   = (__hip_bfloat16*)alloc(15ull * 2048 * 512 * 2);
    __hip_bfloat16* hbuf   = (__hip_bfloat16*)alloc((size_t)M * 2048 * 2);
    // shared region: qkv+ctx (attention phase) overlaid by Y (branch phase)
    const size_t qkv_bytes = (size_t)M * 1536 * 2;            // 67,043,328
    const size_t y_bytes   = 59375616ull * 2;                 // 118,751,232
    char* shared = alloc(y_bytes);                            // >= qkv+ctx
    __hip_bfloat16* qkv = (__hip_bfloat16*)shared;
    __hip_bfloat16* ctx = (__hip_bfloat16*)(shared + qkv_bytes);
    __hip_bfloat16* Y   = (__hip_bfloat16*)shared;
    if (off > ws_size) return;  // workspace too small -> clean validation failure

    auto g128 = [&](const __hip_bfloat16* A, const __hip_bfloat16* Bt,
                    const float* bias, const float* resid, float* Cf,
                    __hip_bfloat16* Cb, int Mr, int N, int K, int flags) {
        int gm = (Mr + 127) >> 7, gn = N >> 7;
        gemm128<<<dim3(gm * gn), 256, 0, stream>>>(
            A, Bt, bias, resid, Cf, Cb, Mr, N, K, flags, gn);
    };

    // weight prep
    transpose_bf16_kernel<<<(512 * 1536 + 255) / 256, 256, 0, stream>>>(w_qkv, wqkvT, 512, 1536, 9);
    transpose_bf16_kernel<<<(512 * 512 + 255) / 256, 256, 0, stream>>>(w_proj, wprojT, 512, 512, 9);
    transpose_bf16_kernel<<<(2048 * 512 + 255) / 256, 256, 0, stream>>>(w2, w2T, 2048, 512, 11);
    pack_wcat_kernel<<<dim3(4096, 15), 256, 0, stream>>>(mlp_M, wcat);

    // attention path
    ln_kernel<<<M, 256, 0, stream>>>(x, ln1_g, ln1_b, xn);
    g128(xn, wqkvT, b_qkv, nullptr, nullptr, qkv, M, 1536, 512, GF_OUTBF16);
    attn_mfma_kernel<<<dim3(512, 2), 256, 0, stream>>>(qkv, ctx);
    g128(ctx, wprojT, b_proj, x, out, nullptr, M, 512, 512, 0);

    // branch MLP path (dedup by source depth s) — single fused dispatch
    ln_kernel<<<M, 256, 0, stream>>>(out, ln2_g, ln2_b, xn);
    gemm_branch_fused<<<dim3(3664), 256, 0, stream>>>(xn, wcat, Y);
    combine_kernel<<<M, 256, 0, stream>>>(Y, mlp_b1, hbuf);
    g128(hbuf, w2T, b2, out, out, nullptr, M, 512, 2048, 0);
}

// Round 4
// 751.484 us; speedup vs baseline: 1.2225x; 1.0450x over previous
//
#include <hip/hip_runtime.h>
#include <hip/hip_bf16.h>

// ---------------------------------------------------------------------------
// Treensformer block: x += MHSA(LN1(x)); x += BranchMLP(LN2(x))
// B=64, N_NODES=341, E=512, H=8, hd=64, 4*E=2048, N_LEVELS=4
// R1: MFMA flash attention. R5: branch-MLP ancestor dedup (Y_s by source
//     depth s; combine kernel). R5 GEMM: 128x128xBK32 register-staged.
// R6/R7: 256x256 deep pipeline -> REGRESSED (w2 164-166us regardless of
//     prefetch depth; 1 block/CU lockstep + shape-wrong for N=512).
// R8: consolidated 128^2 + fused branch dispatch + XCD/A-major remap.
//     RESULT: 785us. w2: FETCH 216->75MB (remap works) but dur 147us
//     unchanged -> NOT memory-bound; chain-latency-bound (~4100cy/iter
//     vs ~300cy MFMA). Conflicts 1.12e7/dispatch = ~256cy/block-iter
//     (64B LDS rows -> 8-way aliasing on every ds_read_b128).
// R9: per-iteration economics, structure unchanged:
//     (a) BK 32->64: halves barrier rendezvous + load-wait events per K
//         (w2 64->32 iters; 32 MFMA per iteration between barriers).
//     (b) m201-family XOR slot swizzle on BOTH ds_write and ds_read
//         (128B rows, slot' = slot ^ (row&7)); register staging so both
//         sides swizzle freely (no global_load_lds constraint).
// ---------------------------------------------------------------------------

typedef __attribute__((ext_vector_type(8))) __bf16 bf16x8;
typedef __attribute__((ext_vector_type(4))) float f32x4;
typedef __attribute__((ext_vector_type(4))) unsigned int u32x4;

#define GF_RELU    1
#define GF_OUTBF16 2

static __device__ __forceinline__ bf16x8 bzero8() {
    u32x4 z = {0u, 0u, 0u, 0u};
    return __builtin_bit_cast(bf16x8, z);
}

// ---------------------------------------------------------------------------
// Weight transpose+convert: out[n*K + k] = bf16(in[k*N + n]); K is pow2.
// ---------------------------------------------------------------------------
__global__ void transpose_bf16_kernel(const float* __restrict__ in,
                                      __hip_bfloat16* __restrict__ out,
                                      int K, int N, int log2K) {
    int idx = blockIdx.x * 256 + threadIdx.x;
    if (idx >= K * N) return;
    int n = idx >> log2K;
    int k = idx & (K - 1);
    out[idx] = __float2bfloat16(in[(size_t)k * N + n]);
}

// ---------------------------------------------------------------------------
// Pack mlp_M (5,5,2048,512) fp32 -> Wcat bf16 grouped by source depth s.
// ---------------------------------------------------------------------------
__global__ void pack_wcat_kernel(const float* __restrict__ M,
                                 __hip_bfloat16* __restrict__ out) {
    int p = blockIdx.y;
    int s, d;
    if (p < 5)       { s = 0; d = p; }
    else if (p < 9)  { s = 1; d = p - 4; }
    else if (p < 12) { s = 2; d = p - 7; }
    else if (p < 14) { s = 3; d = p - 9; }
    else             { s = 4; d = 4; }
    const int base_lut[5] = {0, 5, 9, 12, 14};
    size_t idx = (size_t)blockIdx.x * 256 + threadIdx.x;  // 0 .. 2048*512-1
    const size_t MB = 2048ull * 512;
    out[(size_t)base_lut[s] * MB + (size_t)(d - s) * MB + idx] =
        __float2bfloat16(M[((size_t)d * 5 + s) * MB + idx]);
}

// ---------------------------------------------------------------------------
// LayerNorm over E=512, one block (256 threads) per token; writes bf16.
// ---------------------------------------------------------------------------
__global__ __launch_bounds__(256) void ln_kernel(const float* __restrict__ x,
                                                 const float* __restrict__ g,
                                                 const float* __restrict__ b,
                                                 __hip_bfloat16* __restrict__ out) {
    int tok = blockIdx.x;
    const float* xr = x + (size_t)tok * 512;
    int t = threadIdx.x;
    float v0 = xr[t], v1 = xr[t + 256];
    float s = v0 + v1;
    float s2 = v0 * v0 + v1 * v1;
    #pragma unroll
    for (int o = 32; o > 0; o >>= 1) {
        s  += __shfl_down(s, o);
        s2 += __shfl_down(s2, o);
    }
    __shared__ float ps[4], ps2[4];
    int w = t >> 6, lane = t & 63;
    if (lane == 0) { ps[w] = s; ps2[w] = s2; }
    __syncthreads();
    if (t == 0) {
        float ts = 0.f, ts2 = 0.f;
        #pragma unroll
        for (int i = 0; i < 4; i++) { ts += ps[i]; ts2 += ps2[i]; }
        ps[0] = ts * (1.f / 512.f);
        ps2[0] = ts2 * (1.f / 512.f);
    }
    __syncthreads();
    float m = ps[0];
    float var = ps2[0] - m * m;
    float r = rsqrtf(var + 1e-5f);
    out[(size_t)tok * 512 + t]       = __float2bfloat16((v0 - m) * r * g[t] + b[t]);
    out[(size_t)tok * 512 + t + 256] = __float2bfloat16((v1 - m) * r * g[t + 256] + b[t + 256]);
}

// ---------------------------------------------------------------------------
// MFMA flash attention (unchanged from R2).
// ---------------------------------------------------------------------------
#define ATT_STR 72
__global__ __launch_bounds__(256) void attn_mfma_kernel(const __hip_bfloat16* __restrict__ qkv,
                                                        __hip_bfloat16* __restrict__ ctx) {
    __shared__ __bf16 kt_lds[64 * ATT_STR];
    __shared__ __bf16 vt_lds[64 * ATT_STR];
    __shared__ __bf16 pbuf[4 * 48 * ATT_STR];

    const int bh = blockIdx.x;
    const int half = blockIdx.y;
    const int b = bh >> 3, h = bh & 7;
    const int tid = threadIdx.x;
    const int w = tid >> 6, lane = tid & 63;
    const int q = lane >> 4, l16 = lane & 15;
    const int rowbase = half * 192 + w * 48;
    __bf16* pw = pbuf + w * 48 * ATT_STR;

    bf16x8 qf[3][2];
    #pragma unroll
    for (int mi = 0; mi < 3; mi++) {
        int row = rowbase + mi * 16 + l16;
        #pragma unroll
        for (int ks = 0; ks < 2; ks++) {
            if (row < 341)
                qf[mi][ks] = *(const bf16x8*)(qkv + (size_t)(b * 341 + row) * 1536 +
                                              h * 64 + ks * 32 + q * 8);
            else
                qf[mi][ks] = bzero8();
        }
    }

    f32x4 O[3][4];
    float mrun[3][4], lrun[3][4];
    #pragma unroll
    for (int mi = 0; mi < 3; mi++) {
        #pragma unroll
        for (int ni = 0; ni < 4; ni++) { f32x4 z = {0.f,0.f,0.f,0.f}; O[mi][ni] = z; }
        #pragma unroll
        for (int rr = 0; rr < 4; rr++) { mrun[mi][rr] = -1e30f; lrun[mi][rr] = 0.f; }
    }

    for (int kt6 = 0; kt6 < 6; kt6++) {
        const int kbase = kt6 * 64;
        __syncthreads();
        {
            int key = tid >> 2, kg = tid & 3;
            int gk = kbase + key;
            bf16x8 a0 = bzero8(), a1 = bzero8();
            if (gk < 341) {
                const __hip_bfloat16* src =
                    qkv + (size_t)(b * 341 + gk) * 1536 + 512 + h * 64 + kg * 16;
                a0 = *(const bf16x8*)src;
                a1 = *(const bf16x8*)(src + 8);
            }
            *(bf16x8*)(kt_lds + key * ATT_STR + kg * 16)     = a0;
            *(bf16x8*)(kt_lds + key * ATT_STR + kg * 16 + 8) = a1;
        }
        {
            int key = tid & 63, dg = tid >> 6;
            int gk = kbase + key;
            bf16x8 a0 = bzero8(), a1 = bzero8();
            if (gk < 341) {
                const __hip_bfloat16* src =
                    qkv + (size_t)(b * 341 + gk) * 1536 + 1024 + h * 64 + dg * 16;
                a0 = *(const bf16x8*)src;
                a1 = *(const bf16x8*)(src + 8);
            }
            #pragma unroll
            for (int j = 0; j < 8; j++) {
                vt_lds[(dg * 16 + j) * ATT_STR + key]     = a0[j];
                vt_lds[(dg * 16 + 8 + j) * ATT_STR + key] = a1[j];
            }
        }
        __syncthreads();

        f32x4 S[3][4];
        #pragma unroll
        for (int mi = 0; mi < 3; mi++)
            #pragma unroll
            for (int ni = 0; ni < 4; ni++) { f32x4 z = {0.f,0.f,0.f,0.f}; S[mi][ni] = z; }
        #pragma unroll
        for (int ks = 0; ks < 2; ks++) {
            bf16x8 bf_[4];
            #pragma unroll
            for (int ni = 0; ni < 4; ni++)
                bf_[ni] = *(const bf16x8*)(kt_lds + (ni * 16 + l16) * ATT_STR + ks * 32 + q * 8);
            #pragma unroll
            for (int mi = 0; mi < 3; mi++)
                #pragma unroll
                for (int ni = 0; ni < 4; ni++)
                    S[mi][ni] = __builtin_amdgcn_mfma_f32_16x16x32_bf16(qf[mi][ks], bf_[ni],
                                                                        S[mi][ni], 0, 0, 0);
        }

        float cmask[4];
        #pragma unroll
        for (int ni = 0; ni < 4; ni++)
            cmask[ni] = (kbase + ni * 16 + l16 < 341) ? 0.f : -1e30f;

        #pragma unroll
        for (int mi = 0; mi < 3; mi++) {
            #pragma unroll
            for (int rr = 0; rr < 4; rr++) {
                float rmax = -1e30f;
                #pragma unroll
                for (int ni = 0; ni < 4; ni++)
                    rmax = fmaxf(rmax, fmaf(S[mi][ni][rr], 0.125f, cmask[ni]));
                rmax = fmaxf(rmax, __shfl_xor(rmax, 1));
                rmax = fmaxf(rmax, __shfl_xor(rmax, 2));
                rmax = fmaxf(rmax, __shfl_xor(rmax, 4));
                rmax = fmaxf(rmax, __shfl_xor(rmax, 8));
                float mnew = fmaxf(mrun[mi][rr], rmax);
                float alpha = __expf(mrun[mi][rr] - mnew);
                mrun[mi][rr] = mnew;
                float psum = 0.f;
                #pragma unroll
                for (int ni = 0; ni < 4; ni++) {
                    float p = __expf(fmaf(S[mi][ni][rr], 0.125f, cmask[ni]) - mnew);
                    S[mi][ni][rr] = p;
                    psum += p;
                    O[mi][ni][rr] *= alpha;
                }
                psum += __shfl_xor(psum, 1);
                psum += __shfl_xor(psum, 2);
                psum += __shfl_xor(psum, 4);
                psum += __shfl_xor(psum, 8);
                lrun[mi][rr] = lrun[mi][rr] * alpha + psum;
            }
            #pragma unroll
            for (int ni = 0; ni < 4; ni++)
                #pragma unroll
                for (int rr = 0; rr < 4; rr++)
                    pw[(mi * 16 + q * 4 + rr) * ATT_STR + ni * 16 + l16] =
                        (__bf16)S[mi][ni][rr];
        }
        __syncthreads();

        #pragma unroll
        for (int ks = 0; ks < 2; ks++) {
            bf16x8 pf[3], vf[4];
            #pragma unroll
            for (int mi = 0; mi < 3; mi++)
                pf[mi] = *(const bf16x8*)(pw + (mi * 16 + l16) * ATT_STR + ks * 32 + q * 8);
            #pragma unroll
            for (int ni = 0; ni < 4; ni++)
                vf[ni] = *(const bf16x8*)(vt_lds + (ni * 16 + l16) * ATT_STR + ks * 32 + q * 8);
            #pragma unroll
            for (int mi = 0; mi < 3; mi++)
                #pragma unroll
                for (int ni = 0; ni < 4; ni++)
                    O[mi][ni] = __builtin_amdgcn_mfma_f32_16x16x32_bf16(pf[mi], vf[ni],
                                                                        O[mi][ni], 0, 0, 0);
        }
    }

    #pragma unroll
    for (int mi = 0; mi < 3; mi++) {
        #pragma unroll
        for (int rr = 0; rr < 4; rr++) {
            int row = rowbase + mi * 16 + q * 4 + rr;
            if (row >= 341) continue;
            float inv = 1.f / lrun[mi][rr];
            __hip_bfloat16* op = ctx + (size_t)(b * 341 + row) * 512 + h * 64;
            #pragma unroll
            for (int ni = 0; ni < 4; ni++)
                op[ni * 16 + l16] = __float2bfloat16(O[mi][ni][rr] * inv);
        }
    }
}

// ---------------------------------------------------------------------------
// R9 GEMM body: C(Mrows,N) = A(Mrows,K) @ Bt(N,K)^T [+bias][+resid][relu]
// Tile 128x128xBK64, 256 threads = 4 waves (2x2 of 64x64). Register staging
// (loads hoist above the tile barrier = implicit prefetch). LDS rows are
// 64 elem (128B) = 8 16B slots; slot' = slot ^ (row&7) XOR swizzle applied
// on BOTH ds_write and ds_read (register staging -> both sides free).
// 2 barriers per 32 MFMA (was per 16). Requires K % 64 == 0.
// GATHER: A row gr -> b = gr>>2s, node = offs[s] + (gr & (4^s-1)).
// ---------------------------------------------------------------------------
template <bool GATHER>
static __device__ __forceinline__ void gemm128_body(
    __hip_bfloat16* As, __hip_bfloat16* Bs,
    const __hip_bfloat16* __restrict__ A, const __hip_bfloat16* __restrict__ Bt,
    const float* __restrict__ bias, const float* __restrict__ resid,
    float* __restrict__ Cf, __hip_bfloat16* __restrict__ Cb,
    int Mrows, int N, int K, int flags, int depth, int bm0, int bn0) {
    const int tid = threadIdx.x;
    const int r = tid >> 1;            // staging row 0..127
    const int khalf = tid & 1;         // 0/1 -> 32-element (64B) half of row
    const int gr = bm0 + r;
    const int gn = bn0 + r;
    const int lane = tid & 63;
    const int w = tid >> 6;
    const int wm = (w >> 1) << 6;
    const int wn = (w & 1) << 6;
    const int q = lane >> 4;
    const int l16 = lane & 15;

    // swizzled write slots: slot j (of this thread's half) -> slot ^ (r&7)
    int wsl[4];
    #pragma unroll
    for (int j = 0; j < 4; j++)
        wsl[j] = ((((khalf << 2) | j) ^ (r & 7)) << 3);
    // swizzled read slots for k-slice 0 / 1 (fragment row & 7 == l16 & 7)
    const int rs0 = ((q ^ (l16 & 7)) << 3);
    const int rs1 = (((4 + q) ^ (l16 & 7)) << 3);

    size_t abase;
    if (GATHER) {
        const int dsh = depth << 1;
        const int bmask = (1 << dsh) - 1;
        int b = gr >> dsh;
        int i = gr & bmask;
        int node = (0x55555555 & bmask) + i;   // offs[depth] + i
        abase = ((size_t)(b * 341 + node)) << 9;
    } else {
        abase = (size_t)gr * K;
    }

    f32x4 acc[4][4];
    #pragma unroll
    for (int i = 0; i < 4; i++)
        #pragma unroll
        for (int j = 0; j < 4; j++) {
            f32x4 z = {0.f, 0.f, 0.f, 0.f};
            acc[i][j] = z;
        }

    for (int k0 = 0; k0 < K; k0 += 64) {
        bf16x8 va[4], vb[4];
        if (gr < Mrows) {
            const bf16x8* p = (const bf16x8*)(A + abase + k0 + (khalf << 5));
            #pragma unroll
            for (int j = 0; j < 4; j++) va[j] = p[j];
        } else {
            #pragma unroll
            for (int j = 0; j < 4; j++) va[j] = bzero8();
        }
        {
            const bf16x8* p = (const bf16x8*)(Bt + (size_t)gn * K + k0 + (khalf << 5));
            #pragma unroll
            for (int j = 0; j < 4; j++) vb[j] = p[j];
        }
        __syncthreads();  // previous iteration's fragment reads complete
        #pragma unroll
        for (int j = 0; j < 4; j++) {
            *(bf16x8*)(As + r * 64 + wsl[j]) = va[j];
            *(bf16x8*)(Bs + r * 64 + wsl[j]) = vb[j];
        }
        __syncthreads();
        bf16x8 af[4][2], bfr[4][2];
        #pragma unroll
        for (int mi = 0; mi < 4; mi++) {
            const __hip_bfloat16* rp = As + (wm + mi * 16 + l16) * 64;
            af[mi][0] = *(const bf16x8*)(rp + rs0);
            af[mi][1] = *(const bf16x8*)(rp + rs1);
        }
        #pragma unroll
        for (int ni = 0; ni < 4; ni++) {
            const __hip_bfloat16* rp = Bs + (wn + ni * 16 + l16) * 64;
            bfr[ni][0] = *(const bf16x8*)(rp + rs0);
            bfr[ni][1] = *(const bf16x8*)(rp + rs1);
        }
        #pragma unroll
        for (int ks = 0; ks < 2; ks++)
            #pragma unroll
            for (int mi = 0; mi < 4; mi++)
                #pragma unroll
                for (int ni = 0; ni < 4; ni++)
                    acc[mi][ni] = __builtin_amdgcn_mfma_f32_16x16x32_bf16(
                        af[mi][ks], bfr[ni][ks], acc[mi][ni], 0, 0, 0);
    }

    #pragma unroll
    for (int mi = 0; mi < 4; mi++) {
        #pragma unroll
        for (int rr = 0; rr < 4; rr++) {
            int grow = bm0 + wm + mi * 16 + q * 4 + rr;
            if (grow >= Mrows) continue;
            size_t obase = (size_t)grow * N;
            #pragma unroll
            for (int ni = 0; ni < 4; ni++) {
                int col = bn0 + wn + ni * 16 + l16;
                float v = acc[mi][ni][rr];
                if (bias) v += bias[col];
                if (resid) v += resid[obase + col];
                if (flags & GF_RELU) v = fmaxf(v, 0.f);
                if (flags & GF_OUTBF16)
                    Cb[obase + col] = __float2bfloat16(v);
                else
                    Cf[obase + col] = v;
            }
        }
    }
}

// bijective XCD-aware remap (m204): each XCD gets a contiguous chunk of the
// logical (A-major) tile order -> neighboring tiles sharing an A row-panel
// land on the same XCD's L2.
static __device__ __forceinline__ int xcd_remap(int bid, int nwg) {
    const int xcd = bid & 7, o = bid >> 3;
    const int qq = nwg >> 3, rr = nwg & 7;
    return (xcd < rr ? xcd * (qq + 1) : rr * (qq + 1) + (xcd - rr) * qq) + o;
}

__global__ __launch_bounds__(256) void gemm128(
    const __hip_bfloat16* __restrict__ A, const __hip_bfloat16* __restrict__ Bt,
    const float* __restrict__ bias, const float* __restrict__ resid,
    float* __restrict__ Cf, __hip_bfloat16* __restrict__ Cb,
    int Mrows, int N, int K, int flags, int gridN) {
    __shared__ __hip_bfloat16 As[128 * 64];
    __shared__ __hip_bfloat16 Bs[128 * 64];
    const int lin = xcd_remap(blockIdx.x, gridDim.x);
    const int bx = lin / gridN;           // A-major: consecutive lin share A panel
    const int by = lin - bx * gridN;
    gemm128_body<false>(As, Bs, A, Bt, bias, resid, Cf, Cb,
                        Mrows, N, K, flags, 0, bx << 7, by << 7);
}

// ---------------------------------------------------------------------------
// Fused branch-MLP GEMM: all 5 source-depth levels in ONE 3664-block
// dispatch at 128^2 tiles (s=0: 1x80, s=1: 2x64, s=2: 8x48, s=3: 32x32,
// s=4: 128x16). K=512 for all -> identical per-block work, no serial tails.
// ---------------------------------------------------------------------------
__global__ __launch_bounds__(256) void gemm_branch_fused(
    const __hip_bfloat16* __restrict__ xn, const __hip_bfloat16* __restrict__ wcat,
    __hip_bfloat16* __restrict__ Y) {
    __shared__ __hip_bfloat16 As[128 * 64];
    __shared__ __hip_bfloat16 Bs[128 * 64];
    const int lin = xcd_remap(blockIdx.x, gridDim.x);
    int s;
    if (lin < 80)        s = 0;
    else if (lin < 208)  s = 1;
    else if (lin < 592)  s = 2;
    else if (lin < 1616) s = 3;
    else                 s = 4;
    const int base_tab[5] = {0, 80, 208, 592, 1616};
    const int gn_tab[5]   = {80, 64, 48, 32, 16};
    const size_t yoff[5]  = {0, 655360, 2752512, 9043968, 25821184};
    const int wcat_off[5] = {0, 5, 9, 12, 14};
    const int loc = lin - base_tab[s];
    const int gn = gn_tab[s];
    const int bx = loc / gn;              // A-major within each s
    const int by = loc - bx * gn;
    const int Mrows = 64 << (s << 1);
    const int N = (5 - s) << 11;
    gemm128_body<true>(As, Bs, xn, wcat + (size_t)wcat_off[s] * (2048ull * 512),
                       nullptr, nullptr, nullptr, Y + yoff[s],
                       Mrows, N, 512, GF_OUTBF16, s, bx << 7, by << 7);
}

// ---------------------------------------------------------------------------
// Combine: h[b,node@d,:] = ReLU( sum_{s<=d} Y_s[...] + b1[node] )  (unchanged)
// ---------------------------------------------------------------------------
__global__ __launch_bounds__(256) void combine_kernel(const __hip_bfloat16* __restrict__ Y,
                                                      const float* __restrict__ b1,
                                                      __hip_bfloat16* __restrict__ h) {
    const size_t yoff[5] = {0, 655360, 2752512, 9043968, 25821184};
    int row = blockIdx.x;
    int b = row / 341;
    int node = row - b * 341;
    int d = (node >= 85) ? 4 : (node >= 21) ? 3 : (node >= 5) ? 2 : (node >= 1) ? 1 : 0;
    int i = node - (0x55555555 & ((1 << (d << 1)) - 1));
    int j = threadIdx.x << 3;

    float acc[8];
    const float* bp = b1 + (size_t)node * 2048 + j;
    f32x4 b0 = *(const f32x4*)bp;
    f32x4 b4 = *(const f32x4*)(bp + 4);
    #pragma unroll
    for (int u = 0; u < 4; u++) { acc[u] = b0[u]; acc[u + 4] = b4[u]; }

    #pragma unroll
    for (int s = 0; s < 5; s++) {
        if (s <= d) {
            int a = i >> ((d - s) << 1);
            int width = (5 - s) << 11;
            const bf16x8 v = *(const bf16x8*)(Y + yoff[s] +
                (size_t)((b << (s << 1)) + a) * width + ((d - s) << 11) + j);
            #pragma unroll
            for (int u = 0; u < 8; u++) acc[u] += (float)v[u];
        }
    }
    bf16x8 o;
    #pragma unroll
    for (int u = 0; u < 8; u++) o[u] = (__bf16)fmaxf(acc[u], 0.f);
    *(bf16x8*)(h + (size_t)row * 2048 + j) = o;
}

// ---------------------------------------------------------------------------
extern "C" void kernel_launch(void* const* d_in, const int* in_sizes, int n_in,
                              void* d_out, int out_size, void* d_ws, size_t ws_size,
                              hipStream_t stream) {
    const float* x      = (const float*)d_in[0];
    const float* ln1_g  = (const float*)d_in[1];
    const float* ln1_b  = (const float*)d_in[2];
    const float* w_qkv  = (const float*)d_in[3];
    const float* b_qkv  = (const float*)d_in[4];
    const float* w_proj = (const float*)d_in[5];
    const float* b_proj = (const float*)d_in[6];
    const float* ln2_g  = (const float*)d_in[7];
    const float* ln2_b  = (const float*)d_in[8];
    const float* mlp_M  = (const float*)d_in[9];
    const float* mlp_b1 = (const float*)d_in[10];
    const float* w2     = (const float*)d_in[11];
    const float* b2     = (const float*)d_in[12];
    float* out = (float*)d_out;

    const int M = 64 * 341;  // 21824 rows

    char* ws = (char*)d_ws;
    size_t off = 0;
    auto alloc = [&](size_t bytes) -> char* {
        char* p = ws + off;
        off += (bytes + 255) & ~(size_t)255;
        return p;
    };
    __hip_bfloat16* xn     = (__hip_bfloat16*)alloc((size_t)M * 512 * 2);
    __hip_bfloat16* wqkvT  = (__hip_bfloat16*)alloc(1536ull * 512 * 2);
    __hip_bfloat16* wprojT = (__hip_bfloat16*)alloc(512ull * 512 * 2);
    __hip_bfloat16* w2T    = (__hip_bfloat16*)alloc(512ull * 2048 * 2);
    __hip_bfloat16* wcat   = (__hip_bfloat16*)alloc(15ull * 2048 * 512 * 2);
    __hip_bfloat16* hbuf   = (__hip_bfloat16*)alloc((size_t)M * 2048 * 2);
    // shared region: qkv+ctx (attention phase) overlaid by Y (branch phase)
    const size_t qkv_bytes = (size_t)M * 1536 * 2;            // 67,043,328
    const size_t y_bytes   = 59375616ull * 2;                 // 118,751,232
    char* shared = alloc(y_bytes);                            // >= qkv+ctx
    __hip_bfloat16* qkv = (__hip_bfloat16*)shared;
    __hip_bfloat16* ctx = (__hip_bfloat16*)(shared + qkv_bytes);
    __hip_bfloat16* Y   = (__hip_bfloat16*)shared;
    if (off > ws_size) return;  // workspace too small -> clean validation failure

    auto g128 = [&](const __hip_bfloat16* A, const __hip_bfloat16* Bt,
                    const float* bias, const float* resid, float* Cf,
                    __hip_bfloat16* Cb, int Mr, int N, int K, int flags) {
        int gm = (Mr + 127) >> 7, gn = N >> 7;
        gemm128<<<dim3(gm * gn), 256, 0, stream>>>(
            A, Bt, bias, resid, Cf, Cb, Mr, N, K, flags, gn);
    };

    // weight prep
    transpose_bf16_kernel<<<(512 * 1536 + 255) / 256, 256, 0, stream>>>(w_qkv, wqkvT, 512, 1536, 9);
    transpose_bf16_kernel<<<(512 * 512 + 255) / 256, 256, 0, stream>>>(w_proj, wprojT, 512, 512, 9);
    transpose_bf16_kernel<<<(2048 * 512 + 255) / 256, 256, 0, stream>>>(w2, w2T, 2048, 512, 11);
    pack_wcat_kernel<<<dim3(4096, 15), 256, 0, stream>>>(mlp_M, wcat);

    // attention path
    ln_kernel<<<M, 256, 0, stream>>>(x, ln1_g, ln1_b, xn);
    g128(xn, wqkvT, b_qkv, nullptr, nullptr, qkv, M, 1536, 512, GF_OUTBF16);
    attn_mfma_kernel<<<dim3(512, 2), 256, 0, stream>>>(qkv, ctx);
    g128(ctx, wprojT, b_proj, x, out, nullptr, M, 512, 512, 0);

    // branch MLP path (dedup by source depth s) — single fused dispatch
    ln_kernel<<<M, 256, 0, stream>>>(out, ln2_g, ln2_b, xn);
    gemm_branch_fused<<<dim3(3664), 256, 0, stream>>>(xn, wcat, Y);
    combine_kernel<<<M, 256, 0, stream>>>(Y, mlp_b1, hbuf);
    g128(hbuf, w2T, b2, out, out, nullptr, M, 512, 2048, 0);
}

// Round 5
// 722.144 us; speedup vs baseline: 1.2721x; 1.0406x over previous
//
#include <hip/hip_runtime.h>
#include <hip/hip_bf16.h>

// ---------------------------------------------------------------------------
// Treensformer block: x += MHSA(LN1(x)); x += BranchMLP(LN2(x))
// B=64, N_NODES=341, E=512, H=8, hd=64, 4*E=2048, N_LEVELS=4
// R1: MFMA flash attention. R5: branch-MLP ancestor dedup (Y_s by source
//     depth s; combine kernel). R5 GEMM: 128x128xBK32 register-staged.
// R6/R7: 256x256 deep pipeline -> REGRESSED (lockstep, shape-wrong).
// R8: 128^2 + fused branch + XCD/A-major remap: 785us. FETCH 216->75MB
//     but dur flat -> chain-latency-bound, not memory-bound.
// R9: BK 32->64 + both-sides XOR swizzle: 751us, conflicts 1.1e7->0,
//     w2 147->135. Small -> conflict term was masked. Key remaining fact:
//     72 VGPR + 64 AGPR acc = ~136 unified regs -> 3 waves/SIMD cap, and
//     the N=512 GEMMs only have 684 blocks = 2.67/CU -> grid-bound.
//     Occupancy 23%: the structure lives on inter-block overlap and the
//     machine is 75% empty for proj/w2.
// R10: 64x128xBK64 tile (gemm64) for the narrow GEMMs (proj, w2):
//     1364 blocks (21824=64*341 exact), acc 64->32 AGPR (~4 waves/SIMD),
//     LDS 24KB. Residency ~2.7 -> ~4+ blocks/CU, per-block chain halves.
//     qkv/branch unchanged (already at residency caps) - clean A/B.
// ---------------------------------------------------------------------------

typedef __attribute__((ext_vector_type(8))) __bf16 bf16x8;
typedef __attribute__((ext_vector_type(4))) float f32x4;
typedef __attribute__((ext_vector_type(4))) unsigned int u32x4;

#define GF_RELU    1
#define GF_OUTBF16 2

static __device__ __forceinline__ bf16x8 bzero8() {
    u32x4 z = {0u, 0u, 0u, 0u};
    return __builtin_bit_cast(bf16x8, z);
}

// ---------------------------------------------------------------------------
// Weight transpose+convert: out[n*K + k] = bf16(in[k*N + n]); K is pow2.
// ---------------------------------------------------------------------------
__global__ void transpose_bf16_kernel(const float* __restrict__ in,
                                      __hip_bfloat16* __restrict__ out,
                                      int K, int N, int log2K) {
    int idx = blockIdx.x * 256 + threadIdx.x;
    if (idx >= K * N) return;
    int n = idx >> log2K;
    int k = idx & (K - 1);
    out[idx] = __float2bfloat16(in[(size_t)k * N + n]);
}

// ---------------------------------------------------------------------------
// Pack mlp_M (5,5,2048,512) fp32 -> Wcat bf16 grouped by source depth s.
// ---------------------------------------------------------------------------
__global__ void pack_wcat_kernel(const float* __restrict__ M,
                                 __hip_bfloat16* __restrict__ out) {
    int p = blockIdx.y;
    int s, d;
    if (p < 5)       { s = 0; d = p; }
    else if (p < 9)  { s = 1; d = p - 4; }
    else if (p < 12) { s = 2; d = p - 7; }
    else if (p < 14) { s = 3; d = p - 9; }
    else             { s = 4; d = 4; }
    const int base_lut[5] = {0, 5, 9, 12, 14};
    size_t idx = (size_t)blockIdx.x * 256 + threadIdx.x;  // 0 .. 2048*512-1
    const size_t MB = 2048ull * 512;
    out[(size_t)base_lut[s] * MB + (size_t)(d - s) * MB + idx] =
        __float2bfloat16(M[((size_t)d * 5 + s) * MB + idx]);
}

// ---------------------------------------------------------------------------
// LayerNorm over E=512, one block (256 threads) per token; writes bf16.
// ---------------------------------------------------------------------------
__global__ __launch_bounds__(256) void ln_kernel(const float* __restrict__ x,
                                                 const float* __restrict__ g,
                                                 const float* __restrict__ b,
                                                 __hip_bfloat16* __restrict__ out) {
    int tok = blockIdx.x;
    const float* xr = x + (size_t)tok * 512;
    int t = threadIdx.x;
    float v0 = xr[t], v1 = xr[t + 256];
    float s = v0 + v1;
    float s2 = v0 * v0 + v1 * v1;
    #pragma unroll
    for (int o = 32; o > 0; o >>= 1) {
        s  += __shfl_down(s, o);
        s2 += __shfl_down(s2, o);
    }
    __shared__ float ps[4], ps2[4];
    int w = t >> 6, lane = t & 63;
    if (lane == 0) { ps[w] = s; ps2[w] = s2; }
    __syncthreads();
    if (t == 0) {
        float ts = 0.f, ts2 = 0.f;
        #pragma unroll
        for (int i = 0; i < 4; i++) { ts += ps[i]; ts2 += ps2[i]; }
        ps[0] = ts * (1.f / 512.f);
        ps2[0] = ts2 * (1.f / 512.f);
    }
    __syncthreads();
    float m = ps[0];
    float var = ps2[0] - m * m;
    float r = rsqrtf(var + 1e-5f);
    out[(size_t)tok * 512 + t]       = __float2bfloat16((v0 - m) * r * g[t] + b[t]);
    out[(size_t)tok * 512 + t + 256] = __float2bfloat16((v1 - m) * r * g[t + 256] + b[t + 256]);
}

// ---------------------------------------------------------------------------
// MFMA flash attention (unchanged from R2).
// ---------------------------------------------------------------------------
#define ATT_STR 72
__global__ __launch_bounds__(256) void attn_mfma_kernel(const __hip_bfloat16* __restrict__ qkv,
                                                        __hip_bfloat16* __restrict__ ctx) {
    __shared__ __bf16 kt_lds[64 * ATT_STR];
    __shared__ __bf16 vt_lds[64 * ATT_STR];
    __shared__ __bf16 pbuf[4 * 48 * ATT_STR];

    const int bh = blockIdx.x;
    const int half = blockIdx.y;
    const int b = bh >> 3, h = bh & 7;
    const int tid = threadIdx.x;
    const int w = tid >> 6, lane = tid & 63;
    const int q = lane >> 4, l16 = lane & 15;
    const int rowbase = half * 192 + w * 48;
    __bf16* pw = pbuf + w * 48 * ATT_STR;

    bf16x8 qf[3][2];
    #pragma unroll
    for (int mi = 0; mi < 3; mi++) {
        int row = rowbase + mi * 16 + l16;
        #pragma unroll
        for (int ks = 0; ks < 2; ks++) {
            if (row < 341)
                qf[mi][ks] = *(const bf16x8*)(qkv + (size_t)(b * 341 + row) * 1536 +
                                              h * 64 + ks * 32 + q * 8);
            else
                qf[mi][ks] = bzero8();
        }
    }

    f32x4 O[3][4];
    float mrun[3][4], lrun[3][4];
    #pragma unroll
    for (int mi = 0; mi < 3; mi++) {
        #pragma unroll
        for (int ni = 0; ni < 4; ni++) { f32x4 z = {0.f,0.f,0.f,0.f}; O[mi][ni] = z; }
        #pragma unroll
        for (int rr = 0; rr < 4; rr++) { mrun[mi][rr] = -1e30f; lrun[mi][rr] = 0.f; }
    }

    for (int kt6 = 0; kt6 < 6; kt6++) {
        const int kbase = kt6 * 64;
        __syncthreads();
        {
            int key = tid >> 2, kg = tid & 3;
            int gk = kbase + key;
            bf16x8 a0 = bzero8(), a1 = bzero8();
            if (gk < 341) {
                const __hip_bfloat16* src =
                    qkv + (size_t)(b * 341 + gk) * 1536 + 512 + h * 64 + kg * 16;
                a0 = *(const bf16x8*)src;
                a1 = *(const bf16x8*)(src + 8);
            }
            *(bf16x8*)(kt_lds + key * ATT_STR + kg * 16)     = a0;
            *(bf16x8*)(kt_lds + key * ATT_STR + kg * 16 + 8) = a1;
        }
        {
            int key = tid & 63, dg = tid >> 6;
            int gk = kbase + key;
            bf16x8 a0 = bzero8(), a1 = bzero8();
            if (gk < 341) {
                const __hip_bfloat16* src =
                    qkv + (size_t)(b * 341 + gk) * 1536 + 1024 + h * 64 + dg * 16;
                a0 = *(const bf16x8*)src;
                a1 = *(const bf16x8*)(src + 8);
            }
            #pragma unroll
            for (int j = 0; j < 8; j++) {
                vt_lds[(dg * 16 + j) * ATT_STR + key]     = a0[j];
                vt_lds[(dg * 16 + 8 + j) * ATT_STR + key] = a1[j];
            }
        }
        __syncthreads();

        f32x4 S[3][4];
        #pragma unroll
        for (int mi = 0; mi < 3; mi++)
            #pragma unroll
            for (int ni = 0; ni < 4; ni++) { f32x4 z = {0.f,0.f,0.f,0.f}; S[mi][ni] = z; }
        #pragma unroll
        for (int ks = 0; ks < 2; ks++) {
            bf16x8 bf_[4];
            #pragma unroll
            for (int ni = 0; ni < 4; ni++)
                bf_[ni] = *(const bf16x8*)(kt_lds + (ni * 16 + l16) * ATT_STR + ks * 32 + q * 8);
            #pragma unroll
            for (int mi = 0; mi < 3; mi++)
                #pragma unroll
                for (int ni = 0; ni < 4; ni++)
                    S[mi][ni] = __builtin_amdgcn_mfma_f32_16x16x32_bf16(qf[mi][ks], bf_[ni],
                                                                        S[mi][ni], 0, 0, 0);
        }

        float cmask[4];
        #pragma unroll
        for (int ni = 0; ni < 4; ni++)
            cmask[ni] = (kbase + ni * 16 + l16 < 341) ? 0.f : -1e30f;

        #pragma unroll
        for (int mi = 0; mi < 3; mi++) {
            #pragma unroll
            for (int rr = 0; rr < 4; rr++) {
                float rmax = -1e30f;
                #pragma unroll
                for (int ni = 0; ni < 4; ni++)
                    rmax = fmaxf(rmax, fmaf(S[mi][ni][rr], 0.125f, cmask[ni]));
                rmax = fmaxf(rmax, __shfl_xor(rmax, 1));
                rmax = fmaxf(rmax, __shfl_xor(rmax, 2));
                rmax = fmaxf(rmax, __shfl_xor(rmax, 4));
                rmax = fmaxf(rmax, __shfl_xor(rmax, 8));
                float mnew = fmaxf(mrun[mi][rr], rmax);
                float alpha = __expf(mrun[mi][rr] - mnew);
                mrun[mi][rr] = mnew;
                float psum = 0.f;
                #pragma unroll
                for (int ni = 0; ni < 4; ni++) {
                    float p = __expf(fmaf(S[mi][ni][rr], 0.125f, cmask[ni]) - mnew);
                    S[mi][ni][rr] = p;
                    psum += p;
                    O[mi][ni][rr] *= alpha;
                }
                psum += __shfl_xor(psum, 1);
                psum += __shfl_xor(psum, 2);
                psum += __shfl_xor(psum, 4);
                psum += __shfl_xor(psum, 8);
                lrun[mi][rr] = lrun[mi][rr] * alpha + psum;
            }
            #pragma unroll
            for (int ni = 0; ni < 4; ni++)
                #pragma unroll
                for (int rr = 0; rr < 4; rr++)
                    pw[(mi * 16 + q * 4 + rr) * ATT_STR + ni * 16 + l16] =
                        (__bf16)S[mi][ni][rr];
        }
        __syncthreads();

        #pragma unroll
        for (int ks = 0; ks < 2; ks++) {
            bf16x8 pf[3], vf[4];
            #pragma unroll
            for (int mi = 0; mi < 3; mi++)
                pf[mi] = *(const bf16x8*)(pw + (mi * 16 + l16) * ATT_STR + ks * 32 + q * 8);
            #pragma unroll
            for (int ni = 0; ni < 4; ni++)
                vf[ni] = *(const bf16x8*)(vt_lds + (ni * 16 + l16) * ATT_STR + ks * 32 + q * 8);
            #pragma unroll
            for (int mi = 0; mi < 3; mi++)
                #pragma unroll
                for (int ni = 0; ni < 4; ni++)
                    O[mi][ni] = __builtin_amdgcn_mfma_f32_16x16x32_bf16(pf[mi], vf[ni],
                                                                        O[mi][ni], 0, 0, 0);
        }
    }

    #pragma unroll
    for (int mi = 0; mi < 3; mi++) {
        #pragma unroll
        for (int rr = 0; rr < 4; rr++) {
            int row = rowbase + mi * 16 + q * 4 + rr;
            if (row >= 341) continue;
            float inv = 1.f / lrun[mi][rr];
            __hip_bfloat16* op = ctx + (size_t)(b * 341 + row) * 512 + h * 64;
            #pragma unroll
            for (int ni = 0; ni < 4; ni++)
                op[ni * 16 + l16] = __float2bfloat16(O[mi][ni][rr] * inv);
        }
    }
}

// bijective XCD-aware remap (m204): each XCD gets a contiguous chunk of the
// logical (A-major) tile order -> neighboring tiles sharing an A row-panel
// land on the same XCD's L2.
static __device__ __forceinline__ int xcd_remap(int bid, int nwg) {
    const int xcd = bid & 7, o = bid >> 3;
    const int qq = nwg >> 3, rr = nwg & 7;
    return (xcd < rr ? xcd * (qq + 1) : rr * (qq + 1) + (xcd - rr) * qq) + o;
}

// ---------------------------------------------------------------------------
// R9 GEMM body (128x128xBK64, register staging, both-sides XOR swizzle).
// Used for qkv (N=1536) and the fused branch GEMM (large grids).
// ---------------------------------------------------------------------------
template <bool GATHER>
static __device__ __forceinline__ void gemm128_body(
    __hip_bfloat16* As, __hip_bfloat16* Bs,
    const __hip_bfloat16* __restrict__ A, const __hip_bfloat16* __restrict__ Bt,
    const float* __restrict__ bias, const float* __restrict__ resid,
    float* __restrict__ Cf, __hip_bfloat16* __restrict__ Cb,
    int Mrows, int N, int K, int flags, int depth, int bm0, int bn0) {
    const int tid = threadIdx.x;
    const int r = tid >> 1;            // staging row 0..127
    const int khalf = tid & 1;         // 0/1 -> 32-element (64B) half of row
    const int gr = bm0 + r;
    const int gn = bn0 + r;
    const int lane = tid & 63;
    const int w = tid >> 6;
    const int wm = (w >> 1) << 6;
    const int wn = (w & 1) << 6;
    const int q = lane >> 4;
    const int l16 = lane & 15;

    // swizzled write slots: slot j (of this thread's half) -> slot ^ (r&7)
    int wsl[4];
    #pragma unroll
    for (int j = 0; j < 4; j++)
        wsl[j] = ((((khalf << 2) | j) ^ (r & 7)) << 3);
    // swizzled read slots for k-slice 0 / 1 (fragment row & 7 == l16 & 7)
    const int rs0 = ((q ^ (l16 & 7)) << 3);
    const int rs1 = (((4 + q) ^ (l16 & 7)) << 3);

    size_t abase;
    if (GATHER) {
        const int dsh = depth << 1;
        const int bmask = (1 << dsh) - 1;
        int b = gr >> dsh;
        int i = gr & bmask;
        int node = (0x55555555 & bmask) + i;   // offs[depth] + i
        abase = ((size_t)(b * 341 + node)) << 9;
    } else {
        abase = (size_t)gr * K;
    }

    f32x4 acc[4][4];
    #pragma unroll
    for (int i = 0; i < 4; i++)
        #pragma unroll
        for (int j = 0; j < 4; j++) {
            f32x4 z = {0.f, 0.f, 0.f, 0.f};
            acc[i][j] = z;
        }

    for (int k0 = 0; k0 < K; k0 += 64) {
        bf16x8 va[4], vb[4];
        if (gr < Mrows) {
            const bf16x8* p = (const bf16x8*)(A + abase + k0 + (khalf << 5));
            #pragma unroll
            for (int j = 0; j < 4; j++) va[j] = p[j];
        } else {
            #pragma unroll
            for (int j = 0; j < 4; j++) va[j] = bzero8();
        }
        {
            const bf16x8* p = (const bf16x8*)(Bt + (size_t)gn * K + k0 + (khalf << 5));
            #pragma unroll
            for (int j = 0; j < 4; j++) vb[j] = p[j];
        }
        __syncthreads();  // previous iteration's fragment reads complete
        #pragma unroll
        for (int j = 0; j < 4; j++) {
            *(bf16x8*)(As + r * 64 + wsl[j]) = va[j];
            *(bf16x8*)(Bs + r * 64 + wsl[j]) = vb[j];
        }
        __syncthreads();
        bf16x8 af[4][2], bfr[4][2];
        #pragma unroll
        for (int mi = 0; mi < 4; mi++) {
            const __hip_bfloat16* rp = As + (wm + mi * 16 + l16) * 64;
            af[mi][0] = *(const bf16x8*)(rp + rs0);
            af[mi][1] = *(const bf16x8*)(rp + rs1);
        }
        #pragma unroll
        for (int ni = 0; ni < 4; ni++) {
            const __hip_bfloat16* rp = Bs + (wn + ni * 16 + l16) * 64;
            bfr[ni][0] = *(const bf16x8*)(rp + rs0);
            bfr[ni][1] = *(const bf16x8*)(rp + rs1);
        }
        #pragma unroll
        for (int ks = 0; ks < 2; ks++)
            #pragma unroll
            for (int mi = 0; mi < 4; mi++)
                #pragma unroll
                for (int ni = 0; ni < 4; ni++)
                    acc[mi][ni] = __builtin_amdgcn_mfma_f32_16x16x32_bf16(
                        af[mi][ks], bfr[ni][ks], acc[mi][ni], 0, 0, 0);
    }

    #pragma unroll
    for (int mi = 0; mi < 4; mi++) {
        #pragma unroll
        for (int rr = 0; rr < 4; rr++) {
            int grow = bm0 + wm + mi * 16 + q * 4 + rr;
            if (grow >= Mrows) continue;
            size_t obase = (size_t)grow * N;
            #pragma unroll
            for (int ni = 0; ni < 4; ni++) {
                int col = bn0 + wn + ni * 16 + l16;
                float v = acc[mi][ni][rr];
                if (bias) v += bias[col];
                if (resid) v += resid[obase + col];
                if (flags & GF_RELU) v = fmaxf(v, 0.f);
                if (flags & GF_OUTBF16)
                    Cb[obase + col] = __float2bfloat16(v);
                else
                    Cf[obase + col] = v;
            }
        }
    }
}

__global__ __launch_bounds__(256) void gemm128(
    const __hip_bfloat16* __restrict__ A, const __hip_bfloat16* __restrict__ Bt,
    const float* __restrict__ bias, const float* __restrict__ resid,
    float* __restrict__ Cf, __hip_bfloat16* __restrict__ Cb,
    int Mrows, int N, int K, int flags, int gridN) {
    __shared__ __hip_bfloat16 As[128 * 64];
    __shared__ __hip_bfloat16 Bs[128 * 64];
    const int lin = xcd_remap(blockIdx.x, gridDim.x);
    const int bx = lin / gridN;           // A-major: consecutive lin share A panel
    const int by = lin - bx * gridN;
    gemm128_body<false>(As, Bs, A, Bt, bias, resid, Cf, Cb,
                        Mrows, N, K, flags, 0, bx << 7, by << 7);
}

// ---------------------------------------------------------------------------
// R10 gemm64: 64(M)x128(N)xBK64 for the narrow N=512 GEMMs (proj, w2).
// 256 threads = 4 waves, each wave owns 64x32 (acc[4][2] = 32 AGPR).
// A staging: 4 threads/row x 16 elems (2 slots); B staging: 2 threads/row
// x 32 elems (4 slots) — same XOR slot swizzle as gemm128 on both sides.
// 1364 blocks for M=21824 (=64*341 exact), ~4 blocks/CU residency.
// ---------------------------------------------------------------------------
__global__ __launch_bounds__(256, 4) void gemm64(
    const __hip_bfloat16* __restrict__ A, const __hip_bfloat16* __restrict__ Bt,
    const float* __restrict__ bias, const float* __restrict__ resid,
    float* __restrict__ Cf, __hip_bfloat16* __restrict__ Cb,
    int Mrows, int N, int K, int flags, int gridN) {
    __shared__ __hip_bfloat16 As[64 * 64];
    __shared__ __hip_bfloat16 Bs[128 * 64];
    const int lin = xcd_remap(blockIdx.x, gridDim.x);
    const int bx = lin / gridN;           // A-major
    const int by = lin - bx * gridN;
    const int bm0 = bx << 6, bn0 = by << 7;

    const int tid = threadIdx.x;
    const int ra = tid >> 2, kq = tid & 3;      // A: 4 threads/row, 2 slots
    const int rb = tid >> 1, khalf = tid & 1;   // B: 2 threads/row, 4 slots
    const int lane = tid & 63;
    const int w = tid >> 6;
    const int wn = w << 5;                      // wave col offset 0/32/64/96
    const int q = lane >> 4;
    const int l16 = lane & 15;

    const int gra = bm0 + ra;
    const int gnb = bn0 + rb;

    int wslA[2];
    #pragma unroll
    for (int j = 0; j < 2; j++)
        wslA[j] = ((((kq << 1) | j) ^ (ra & 7)) << 3);
    int wslB[4];
    #pragma unroll
    for (int j = 0; j < 4; j++)
        wslB[j] = ((((khalf << 2) | j) ^ (rb & 7)) << 3);
    const int rs0 = ((q ^ (l16 & 7)) << 3);
    const int rs1 = (((4 + q) ^ (l16 & 7)) << 3);

    const size_t abase = (size_t)gra * K;

    f32x4 acc[4][2];
    #pragma unroll
    for (int i = 0; i < 4; i++)
        #pragma unroll
        for (int j = 0; j < 2; j++) {
            f32x4 z = {0.f, 0.f, 0.f, 0.f};
            acc[i][j] = z;
        }

    for (int k0 = 0; k0 < K; k0 += 64) {
        bf16x8 va[2], vb[4];
        if (gra < Mrows) {
            const bf16x8* p = (const bf16x8*)(A + abase + k0 + (kq << 4));
            #pragma unroll
            for (int j = 0; j < 2; j++) va[j] = p[j];
        } else {
            #pragma unroll
            for (int j = 0; j < 2; j++) va[j] = bzero8();
        }
        {
            const bf16x8* p = (const bf16x8*)(Bt + (size_t)gnb * K + k0 + (khalf << 5));
            #pragma unroll
            for (int j = 0; j < 4; j++) vb[j] = p[j];
        }
        __syncthreads();  // previous iteration's fragment reads complete
        #pragma unroll
        for (int j = 0; j < 2; j++)
            *(bf16x8*)(As + ra * 64 + wslA[j]) = va[j];
        #pragma unroll
        for (int j = 0; j < 4; j++)
            *(bf16x8*)(Bs + rb * 64 + wslB[j]) = vb[j];
        __syncthreads();
        bf16x8 af[4][2], bfr[2][2];
        #pragma unroll
        for (int mi = 0; mi < 4; mi++) {
            const __hip_bfloat16* rp = As + (mi * 16 + l16) * 64;
            af[mi][0] = *(const bf16x8*)(rp + rs0);
            af[mi][1] = *(const bf16x8*)(rp + rs1);
        }
        #pragma unroll
        for (int ni = 0; ni < 2; ni++) {
            const __hip_bfloat16* rp = Bs + (wn + ni * 16 + l16) * 64;
            bfr[ni][0] = *(const bf16x8*)(rp + rs0);
            bfr[ni][1] = *(const bf16x8*)(rp + rs1);
        }
        #pragma unroll
        for (int ks = 0; ks < 2; ks++)
            #pragma unroll
            for (int mi = 0; mi < 4; mi++)
                #pragma unroll
                for (int ni = 0; ni < 2; ni++)
                    acc[mi][ni] = __builtin_amdgcn_mfma_f32_16x16x32_bf16(
                        af[mi][ks], bfr[ni][ks], acc[mi][ni], 0, 0, 0);
    }

    #pragma unroll
    for (int mi = 0; mi < 4; mi++) {
        #pragma unroll
        for (int rr = 0; rr < 4; rr++) {
            int grow = bm0 + mi * 16 + q * 4 + rr;
            if (grow >= Mrows) continue;
            size_t obase = (size_t)grow * N;
            #pragma unroll
            for (int ni = 0; ni < 2; ni++) {
                int col = bn0 + wn + ni * 16 + l16;
                float v = acc[mi][ni][rr];
                if (bias) v += bias[col];
                if (resid) v += resid[obase + col];
                if (flags & GF_RELU) v = fmaxf(v, 0.f);
                if (flags & GF_OUTBF16)
                    Cb[obase + col] = __float2bfloat16(v);
                else
                    Cf[obase + col] = v;
            }
        }
    }
}

// ---------------------------------------------------------------------------
// Fused branch-MLP GEMM: all 5 source-depth levels in ONE 3664-block
// dispatch at 128^2 tiles (s=0: 1x80, s=1: 2x64, s=2: 8x48, s=3: 32x32,
// s=4: 128x16). K=512 for all -> identical per-block work, no serial tails.
// ---------------------------------------------------------------------------
__global__ __launch_bounds__(256) void gemm_branch_fused(
    const __hip_bfloat16* __restrict__ xn, const __hip_bfloat16* __restrict__ wcat,
    __hip_bfloat16* __restrict__ Y) {
    __shared__ __hip_bfloat16 As[128 * 64];
    __shared__ __hip_bfloat16 Bs[128 * 64];
    const int lin = xcd_remap(blockIdx.x, gridDim.x);
    int s;
    if (lin < 80)        s = 0;
    else if (lin < 208)  s = 1;
    else if (lin < 592)  s = 2;
    else if (lin < 1616) s = 3;
    else                 s = 4;
    const int base_tab[5] = {0, 80, 208, 592, 1616};
    const int gn_tab[5]   = {80, 64, 48, 32, 16};
    const size_t yoff[5]  = {0, 655360, 2752512, 9043968, 25821184};
    const int wcat_off[5] = {0, 5, 9, 12, 14};
    const int loc = lin - base_tab[s];
    const int gn = gn_tab[s];
    const int bx = loc / gn;              // A-major within each s
    const int by = loc - bx * gn;
    const int Mrows = 64 << (s << 1);
    const int N = (5 - s) << 11;
    gemm128_body<true>(As, Bs, xn, wcat + (size_t)wcat_off[s] * (2048ull * 512),
                       nullptr, nullptr, nullptr, Y + yoff[s],
                       Mrows, N, 512, GF_OUTBF16, s, bx << 7, by << 7);
}

// ---------------------------------------------------------------------------
// Combine: h[b,node@d,:] = ReLU( sum_{s<=d} Y_s[...] + b1[node] )  (unchanged)
// ---------------------------------------------------------------------------
__global__ __launch_bounds__(256) void combine_kernel(const __hip_bfloat16* __restrict__ Y,
                                                      const float* __restrict__ b1,
                                                      __hip_bfloat16* __restrict__ h) {
    const size_t yoff[5] = {0, 655360, 2752512, 9043968, 25821184};
    int row = blockIdx.x;
    int b = row / 341;
    int node = row - b * 341;
    int d = (node >= 85) ? 4 : (node >= 21) ? 3 : (node >= 5) ? 2 : (node >= 1) ? 1 : 0;
    int i = node - (0x55555555 & ((1 << (d << 1)) - 1));
    int j = threadIdx.x << 3;

    float acc[8];
    const float* bp = b1 + (size_t)node * 2048 + j;
    f32x4 b0 = *(const f32x4*)bp;
    f32x4 b4 = *(const f32x4*)(bp + 4);
    #pragma unroll
    for (int u = 0; u < 4; u++) { acc[u] = b0[u]; acc[u + 4] = b4[u]; }

    #pragma unroll
    for (int s = 0; s < 5; s++) {
        if (s <= d) {
            int a = i >> ((d - s) << 1);
            int width = (5 - s) << 11;
            const bf16x8 v = *(const bf16x8*)(Y + yoff[s] +
                (size_t)((b << (s << 1)) + a) * width + ((d - s) << 11) + j);
            #pragma unroll
            for (int u = 0; u < 8; u++) acc[u] += (float)v[u];
        }
    }
    bf16x8 o;
    #pragma unroll
    for (int u = 0; u < 8; u++) o[u] = (__bf16)fmaxf(acc[u], 0.f);
    *(bf16x8*)(h + (size_t)row * 2048 + j) = o;
}

// ---------------------------------------------------------------------------
extern "C" void kernel_launch(void* const* d_in, const int* in_sizes, int n_in,
                              void* d_out, int out_size, void* d_ws, size_t ws_size,
                              hipStream_t stream) {
    const float* x      = (const float*)d_in[0];
    const float* ln1_g  = (const float*)d_in[1];
    const float* ln1_b  = (const float*)d_in[2];
    const float* w_qkv  = (const float*)d_in[3];
    const float* b_qkv  = (const float*)d_in[4];
    const float* w_proj = (const float*)d_in[5];
    const float* b_proj = (const float*)d_in[6];
    const float* ln2_g  = (const float*)d_in[7];
    const float* ln2_b  = (const float*)d_in[8];
    const float* mlp_M  = (const float*)d_in[9];
    const float* mlp_b1 = (const float*)d_in[10];
    const float* w2     = (const float*)d_in[11];
    const float* b2     = (const float*)d_in[12];
    float* out = (float*)d_out;

    const int M = 64 * 341;  // 21824 rows

    char* ws = (char*)d_ws;
    size_t off = 0;
    auto alloc = [&](size_t bytes) -> char* {
        char* p = ws + off;
        off += (bytes + 255) & ~(size_t)255;
        return p;
    };
    __hip_bfloat16* xn     = (__hip_bfloat16*)alloc((size_t)M * 512 * 2);
    __hip_bfloat16* wqkvT  = (__hip_bfloat16*)alloc(1536ull * 512 * 2);
    __hip_bfloat16* wprojT = (__hip_bfloat16*)alloc(512ull * 512 * 2);
    __hip_bfloat16* w2T    = (__hip_bfloat16*)alloc(512ull * 2048 * 2);
    __hip_bfloat16* wcat   = (__hip_bfloat16*)alloc(15ull * 2048 * 512 * 2);
    __hip_bfloat16* hbuf   = (__hip_bfloat16*)alloc((size_t)M * 2048 * 2);
    // shared region: qkv+ctx (attention phase) overlaid by Y (branch phase)
    const size_t qkv_bytes = (size_t)M * 1536 * 2;            // 67,043,328
    const size_t y_bytes   = 59375616ull * 2;                 // 118,751,232
    char* shared = alloc(y_bytes);                            // >= qkv+ctx
    __hip_bfloat16* qkv = (__hip_bfloat16*)shared;
    __hip_bfloat16* ctx = (__hip_bfloat16*)(shared + qkv_bytes);
    __hip_bfloat16* Y   = (__hip_bfloat16*)shared;
    if (off > ws_size) return;  // workspace too small -> clean validation failure

    auto g128 = [&](const __hip_bfloat16* A, const __hip_bfloat16* Bt,
                    const float* bias, const float* resid, float* Cf,
                    __hip_bfloat16* Cb, int Mr, int N, int K, int flags) {
        int gm = (Mr + 127) >> 7, gn = N >> 7;
        gemm128<<<dim3(gm * gn), 256, 0, stream>>>(
            A, Bt, bias, resid, Cf, Cb, Mr, N, K, flags, gn);
    };
    auto g64 = [&](const __hip_bfloat16* A, const __hip_bfloat16* Bt,
                   const float* bias, const float* resid, float* Cf,
                   __hip_bfloat16* Cb, int Mr, int N, int K, int flags) {
        int gm = (Mr + 63) >> 6, gn = N >> 7;
        gemm64<<<dim3(gm * gn), 256, 0, stream>>>(
            A, Bt, bias, resid, Cf, Cb, Mr, N, K, flags, gn);
    };

    // weight prep
    transpose_bf16_kernel<<<(512 * 1536 + 255) / 256, 256, 0, stream>>>(w_qkv, wqkvT, 512, 1536, 9);
    transpose_bf16_kernel<<<(512 * 512 + 255) / 256, 256, 0, stream>>>(w_proj, wprojT, 512, 512, 9);
    transpose_bf16_kernel<<<(2048 * 512 + 255) / 256, 256, 0, stream>>>(w2, w2T, 2048, 512, 11);
    pack_wcat_kernel<<<dim3(4096, 15), 256, 0, stream>>>(mlp_M, wcat);

    // attention path
    ln_kernel<<<M, 256, 0, stream>>>(x, ln1_g, ln1_b, xn);
    g128(xn, wqkvT, b_qkv, nullptr, nullptr, qkv, M, 1536, 512, GF_OUTBF16);
    attn_mfma_kernel<<<dim3(512, 2), 256, 0, stream>>>(qkv, ctx);
    g64(ctx, wprojT, b_proj, x, out, nullptr, M, 512, 512, 0);

    // branch MLP path (dedup by source depth s) — single fused dispatch
    ln_kernel<<<M, 256, 0, stream>>>(out, ln2_g, ln2_b, xn);
    gemm_branch_fused<<<dim3(3664), 256, 0, stream>>>(xn, wcat, Y);
    combine_kernel<<<M, 256, 0, stream>>>(Y, mlp_b1, hbuf);
    g64(hbuf, w2T, b2, out, out, nullptr, M, 512, 2048, 0);
}